// Round 9
// baseline (278.017 us; speedup 1.0000x reference)
//
#include <hip/hip_runtime.h>
#include <cmath>

#define R_TOT 4096   // B*S rows
#define HID   768
#define NHEAD 12
#define HDIM  64
#define SEQ   512
#define BATCH 8

typedef int   v4i  __attribute__((ext_vector_type(4)));
typedef float v4f  __attribute__((ext_vector_type(4)));
typedef _Float16 half8 __attribute__((ext_vector_type(8)));
typedef _Float16 half4v __attribute__((ext_vector_type(4)));

// ---------------- PLA coefficients (host, replicates np.polyfit in f64) ----
struct PlaConsts { float m[12]; float c[12]; float b[13]; };

static PlaConsts build_pla() {
  PlaConsts pc;
  const int NPTS = 1001;
  static double xs[NPTS], ys[NPTS];
  const double step = 10.0 / 1000.0;
  for (int j = 0; j < NPTS; ++j) xs[j] = (double)j * step + (-10.0);
  xs[NPTS - 1] = 0.0;
  for (int j = 0; j < NPTS; ++j) ys[j] = std::exp(xs[j]);
  double bnd[13];
  const double step2 = 10.0 / 12.0;
  for (int k = 0; k < 13; ++k) bnd[k] = (double)k * step2 + (-10.0);
  bnd[12] = 0.0;
  for (int i = 0; i < 12; ++i) {
    const double a = bnd[i], bb = bnd[i + 1];
    double sx = 0, sy = 0; int n = 0;
    for (int j = 0; j < NPTS; ++j)
      if (xs[j] >= a && xs[j] <= bb) { sx += xs[j]; sy += ys[j]; ++n; }
    const double xm = sx / n, ym = sy / n;
    double sxx = 0, sxy = 0;
    for (int j = 0; j < NPTS; ++j)
      if (xs[j] >= a && xs[j] <= bb) {
        const double dx = xs[j] - xm;
        sxx += dx * dx; sxy += dx * (ys[j] - ym);
      }
    const double m = sxy / sxx;
    pc.m[i] = (float)m;
    pc.c[i] = (float)(ym - m * xm);
  }
  for (int k = 0; k < 13; ++k) pc.b[k] = (float)bnd[k];
  return pc;
}
static const PlaConsts g_pla = build_pla();

// ---------------- per-row abs-max int8 quantization -----------------------
__device__ __forceinline__ void quant_row_body(const float* __restrict__ x,
                                               signed char* __restrict__ qrow,
                                               float* __restrict__ srow,
                                               int ncols) {
  float m = 0.f;
  for (int c = threadIdx.x; c < ncols; c += 256)
    m = fmaxf(m, fabsf(x[c]));
  #pragma unroll
  for (int off = 32; off; off >>= 1) m = fmaxf(m, __shfl_xor(m, off));
  __shared__ float red[4];
  const int lane = threadIdx.x & 63, wv = threadIdx.x >> 6;
  if (lane == 0) red[wv] = m;
  __syncthreads();
  if (threadIdx.x == 0) {
    float mm = fmaxf(fmaxf(red[0], red[1]), fmaxf(red[2], red[3]));
    float s = mm / 127.0f;
    if (s == 0.f) s = 1.f;
    red[0] = s;
    *srow = s;
  }
  __syncthreads();
  const float s = red[0];
  for (int c = threadIdx.x; c < ncols; c += 256) {
    float q = rintf(x[c] / s);
    q = fminf(fmaxf(q, -127.f), 127.f);
    qrow[c] = (signed char)(int)q;
  }
}

__global__ __launch_bounds__(256)
void quant_rows(const float* __restrict__ src, int ncols,
                signed char* __restrict__ qout, float* __restrict__ sout) {
  const int row = blockIdx.x;
  quant_row_body(src + (size_t)row * ncols, qout + (size_t)row * ncols,
                 sout + row, ncols);
}

// hidden states (4096 rows) + 4 weight matrices (4x768 rows) in ONE launch
__global__ __launch_bounds__(256)
void quant_all(const float* hs, const float* w0, const float* w1,
               const float* w2, const float* w3,
               signed char* qx, float* sx,
               signed char* q0, signed char* q1, signed char* q2, signed char* q3,
               float* s0, float* s1, float* s2, float* s3) {
  const int bid = blockIdx.x;
  const float* src; signed char* qo; float* so; int row;
  if (bid < R_TOT)            { src = hs; qo = qx; so = sx; row = bid; }
  else if (bid < R_TOT + 768) { src = w0; qo = q0; so = s0; row = bid - R_TOT; }
  else if (bid < R_TOT + 1536){ src = w1; qo = q1; so = s1; row = bid - R_TOT - 768; }
  else if (bid < R_TOT + 2304){ src = w2; qo = q2; so = s2; row = bid - R_TOT - 1536; }
  else                        { src = w3; qo = q3; so = s3; row = bid - R_TOT - 2304; }
  quant_row_body(src + (size_t)row * HID, qo + (size_t)row * HID, so + row, HID);
}

// ---------------- int8 MFMA GEMM body: 128x64 tile, BK=128 -----------------
// mode 0: fp32 dense out; mode 1: per-head int8 (bhsd) + scales;
// mode 2: V path -> fp16 k-chunked transposed vt2[hb][k>>5][d][k&31]
__device__ __forceinline__
void proj_body(int mode,
               const signed char* __restrict__ qx, const float* __restrict__ sx,
               const signed char* __restrict__ qw, const float* __restrict__ sw,
               const float* __restrict__ bias,
               signed char* __restrict__ qo, float* __restrict__ so,
               _Float16* __restrict__ vt, float* __restrict__ fo,
               signed char* Al, signed char* Bl) {
  const int tid = threadIdx.x;
  const int w = tid >> 6, lane = tid & 63;
  const int n = lane & 15, quad = lane >> 4;
  const int row0 = blockIdx.x * 128, col0 = blockIdx.y * 64;
  const int ar = tid >> 1, ac = (tid & 1) * 64;   // A: 1 row, 64B contiguous
  const int br = tid >> 2, bc = (tid & 3) * 32;   // B: 1 row, 32B contiguous
  v4i acc[2][4];
  #pragma unroll
  for (int s = 0; s < 2; ++s)
    #pragma unroll
    for (int j = 0; j < 4; ++j) acc[s][j] = (v4i){0, 0, 0, 0};
  for (int k0 = 0; k0 < HID; k0 += 128) {
    const signed char* ap = qx + (size_t)(row0 + ar) * HID + k0 + ac;
    const int4 a0 = *(const int4*)(ap);
    const int4 a1 = *(const int4*)(ap + 16);
    const int4 a2 = *(const int4*)(ap + 32);
    const int4 a3 = *(const int4*)(ap + 48);
    const signed char* bp = qw + (size_t)(col0 + br) * HID + k0 + bc;
    const int4 b0 = *(const int4*)(bp);
    const int4 b1 = *(const int4*)(bp + 16);
    if (k0) __syncthreads();
    *(int4*)&Al[ar * 144 + ac]      = a0;
    *(int4*)&Al[ar * 144 + ac + 16] = a1;
    *(int4*)&Al[ar * 144 + ac + 32] = a2;
    *(int4*)&Al[ar * 144 + ac + 48] = a3;
    *(int4*)&Bl[br * 144 + bc]      = b0;
    *(int4*)&Bl[br * 144 + bc + 16] = b1;
    __syncthreads();
    #pragma unroll
    for (int ks = 0; ks < 128; ks += 64) {
      const v4i af0 = *(const v4i*)&Al[(w * 16 + n) * 144 + ks + quad * 16];
      const v4i af1 = *(const v4i*)&Al[(64 + w * 16 + n) * 144 + ks + quad * 16];
      #pragma unroll
      for (int j = 0; j < 4; ++j) {
        const v4i bf = *(const v4i*)&Bl[(j * 16 + n) * 144 + ks + quad * 16];
        acc[0][j] = __builtin_amdgcn_mfma_i32_16x16x64_i8(af0, bf, acc[0][j], 0, 0, 0);
        acc[1][j] = __builtin_amdgcn_mfma_i32_16x16x64_i8(af1, bf, acc[1][j], 0, 0, 0);
      }
    }
  }
  float swc4[4], bc4[4];
  #pragma unroll
  for (int j = 0; j < 4; ++j) {
    swc4[j] = sw[col0 + j * 16 + n];
    bc4[j] = bias[col0 + j * 16 + n];
  }
  #pragma unroll
  for (int s = 0; s < 2; ++s) {
    const int mrow = s * 64 + w * 16 + quad * 4;
    float sxr[4];
    #pragma unroll
    for (int r = 0; r < 4; ++r) sxr[r] = sx[row0 + mrow + r];
    float vals[4][4];  // [j][r]
    #pragma unroll
    for (int j = 0; j < 4; ++j)
      #pragma unroll
      for (int r = 0; r < 4; ++r)
        vals[j][r] = (float)acc[s][j][r] * (sxr[r] * swc4[j]) + bc4[j];
    if (mode == 1) {
      const int h = blockIdx.y;
      #pragma unroll
      for (int r = 0; r < 4; ++r) {
        float m = 0.f;
        #pragma unroll
        for (int j = 0; j < 4; ++j) m = fmaxf(m, fabsf(vals[j][r]));
        #pragma unroll
        for (int off = 1; off < 16; off <<= 1) m = fmaxf(m, __shfl_xor(m, off));
        float sq = m / 127.0f;
        if (sq == 0.f) sq = 1.f;
        const int grow = row0 + mrow + r;
        const int bidx = grow >> 9, sidx = grow & 511;
        const size_t rowidx = ((size_t)bidx * NHEAD + h) * SEQ + sidx;
        #pragma unroll
        for (int j = 0; j < 4; ++j) {
          float q = fminf(fmaxf(rintf(vals[j][r] / sq), -127.f), 127.f);
          qo[rowidx * HDIM + j * 16 + n] = (signed char)(int)q;
        }
        if (n == 0) so[rowidx] = sq;
      }
    } else if (mode == 2) {
      const int h = blockIdx.y;
      float srow[4];
      #pragma unroll
      for (int r = 0; r < 4; ++r) {
        float m = 0.f;
        #pragma unroll
        for (int j = 0; j < 4; ++j) m = fmaxf(m, fabsf(vals[j][r]));
        #pragma unroll
        for (int off = 1; off < 16; off <<= 1) m = fmaxf(m, __shfl_xor(m, off));
        float sq = m / 127.0f;
        if (sq == 0.f) sq = 1.f;
        srow[r] = sq;
      }
      const int grow0 = row0 + mrow;         // 4 consecutive k, same batch
      const int bidx = grow0 >> 9, sidx = grow0 & 511;
      const int kb = sidx >> 5, ko = sidx & 31;
      const size_t hbv = (size_t)bidx * NHEAD + h;
      #pragma unroll
      for (int j = 0; j < 4; ++j) {
        half4v hv;
        #pragma unroll
        for (int r = 0; r < 4; ++r) {
          float q = fminf(fmaxf(rintf(vals[j][r] / srow[r]), -127.f), 127.f);
          hv[r] = (_Float16)(q * srow[r]);
        }
        *(half4v*)(vt + ((hbv * 16 + kb) * 64 + j * 16 + n) * 32 + ko) = hv;
      }
    } else {
      #pragma unroll
      for (int r = 0; r < 4; ++r) {
        const size_t base = (size_t)(row0 + mrow + r) * HID + col0;
        #pragma unroll
        for (int j = 0; j < 4; ++j)
          fo[base + j * 16 + n] = vals[j][r];
      }
    }
  }
}

// fused Q/K/V projections: blockIdx.z selects weight/output
__global__ __launch_bounds__(256)
void proj_qkv(const signed char* __restrict__ qx, const float* __restrict__ sx,
              const signed char* qwq, const float* swq, const float* bq,
              signed char* qqd, float* qqs,
              const signed char* qwk, const float* swk, const float* bk,
              signed char* qkd, float* qks,
              const signed char* qwv, const float* swv, const float* bv,
              _Float16* vt2) {
  __shared__ __align__(16) signed char Al[128 * 144];
  __shared__ __align__(16) signed char Bl[64 * 144];
  if (blockIdx.z == 0)
    proj_body(1, qx, sx, qwq, swq, bq, qqd, qqs, nullptr, nullptr, Al, Bl);
  else if (blockIdx.z == 1)
    proj_body(1, qx, sx, qwk, swk, bk, qkd, qks, nullptr, nullptr, Al, Bl);
  else
    proj_body(2, qx, sx, qwv, swv, bv, nullptr, nullptr, vt2, nullptr, Al, Bl);
}

__global__ __launch_bounds__(256)
void proj_out(const signed char* __restrict__ qx, const float* __restrict__ sx,
              const signed char* qw, const float* sw, const float* bias,
              float* fo) {
  __shared__ __align__(16) signed char Al[128 * 144];
  __shared__ __align__(16) signed char Bl[64 * 144];
  proj_body(0, qx, sx, qw, sw, bias, nullptr, nullptr, nullptr, fo, Al, Bl);
}

// ---------------- fused attention: 32 q-rows/block, per-tile loop ----------
// One 16-row tile at a time through a single PhT buffer: LDS 17.7 KB,
// VGPR ~80 (s26 halved) -> ~6 blocks/CU. K/V read twice per block (L2-hot).
#define PSTR 520  // PhT row stride in halves (16B-aligned rows)
__global__ __launch_bounds__(256, 6)
void attn_kernel(const signed char* __restrict__ qq, const float* __restrict__ qss,
                 const signed char* __restrict__ qk, const float* __restrict__ kss,
                 const _Float16* __restrict__ vt2,
                 float* __restrict__ ctx, const PlaConsts pc) {
  __shared__ __align__(16) _Float16 PhT[16 * PSTR];  // quantized probs (1 tile)
  __shared__ __align__(16) float red_max[16][4];
  __shared__ __align__(16) float red_sum[16][4];
  __shared__ __align__(16) float red_amax[16][4];
  __shared__ float psa[16];
  __shared__ __align__(8) float pb2[12][2];
  __shared__ __align__(8) float pmc[12][2];

  const int tid = threadIdx.x;
  const int q0 = blockIdx.x * 32;
  const int hh = blockIdx.y, bz = blockIdx.z;
  const size_t hb = (size_t)bz * NHEAD + hh;
  const signed char* qkh = qk + hb * SEQ * HDIM;
  const float* ksp = kss + hb * SEQ;

  if (tid < 12) {
    pb2[tid][0] = pc.b[tid]; pb2[tid][1] = pc.b[tid + 1];
    pmc[tid][0] = pc.m[tid]; pmc[tid][1] = pc.c[tid];
  }

  const int w = tid >> 6, lane = tid & 63;
  const int n = lane & 15, quad = lane >> 4;

  for (int tau = 0; tau < 2; ++tau) {
    const int qb = q0 + tau * 16;
    const signed char* qqh = qq + (hb * SEQ + qb) * HDIM;

    // ---- Phase 1: S^T via i8 MFMA (A=K rows, B=Q rows) ----
    float s26[8][4];
    {
      const v4i qf0 = *(const v4i*)(qqh + (size_t)n * HDIM + quad * 16);
      const float qs0 = (qss[hb * SEQ + qb + n] * 0.125f) * 67108864.0f;
      float vmax0 = -3.0e38f;
      #pragma unroll
      for (int t = 0; t < 8; ++t) {
        const int kc0 = (t * 4 + w) * 16;
        const v4i kfrag = *(const v4i*)(qkh + (size_t)(kc0 + n) * HDIM + quad * 16);
        const float4 ks4 = *(const float4*)(ksp + kc0 + quad * 4);
        v4i zero = {};
        const v4i a0 = __builtin_amdgcn_mfma_i32_16x16x64_i8(kfrag, qf0, zero, 0, 0, 0);
        const float ks[4] = {ks4.x, ks4.y, ks4.z, ks4.w};
        #pragma unroll
        for (int r = 0; r < 4; ++r) {
          const float v0 = (float)a0[r] * (qs0 * ks[r]);
          s26[t][r] = v0; vmax0 = fmaxf(vmax0, v0);
        }
      }
      vmax0 = fmaxf(vmax0, __shfl_xor(vmax0, 16));
      vmax0 = fmaxf(vmax0, __shfl_xor(vmax0, 32));
      if (quad == 0) red_max[n][w] = vmax0;
    }
    __syncthreads();

    // ---- Phase 2a: PLA exp (one row per lane), partial sums ----
    {
      const float4 rm = *(const float4*)&red_max[n][0];
      const float mx26 = fmaxf(fmaxf(rm.x, rm.y), fmaxf(rm.z, rm.w));
      float sum = 0.f, amax = 0.f;
      #pragma unroll
      for (int t = 0; t < 8; ++t) {
        #pragma unroll
        for (int r = 0; r < 4; ++r) {
          float sh = s26[t][r] - mx26;            // == (s-mx)*2^26 exactly
          sh = fmaxf(sh, -671088640.0f);          // clamp at -10*2^26
          const float tq = rintf(sh);
          const float xc = tq * 1.4901161193847656e-08f;  // *2^-26 (exact)
          int g = (int)floorf((xc + 10.0f) * 1.2f);
          g = g < 0 ? 0 : (g > 11 ? 11 : g);
          const float2 bb = *(const float2*)&pb2[g][0];
          if (xc < bb.x) --g;
          else if (xc >= bb.y) ++g;
          g = g < 0 ? 0 : (g > 11 ? 11 : g);
          const float2 mc = *(const float2*)&pmc[g][0];
          const float e = __fadd_rn(__fmul_rn(mc.x, xc), mc.y);
          s26[t][r] = e;
          sum += e;
          amax = fmaxf(amax, fabsf(e));
        }
      }
      sum += __shfl_xor(sum, 16);
      sum += __shfl_xor(sum, 32);
      amax = fmaxf(amax, __shfl_xor(amax, 16));
      amax = fmaxf(amax, __shfl_xor(amax, 32));
      if (quad == 0) { red_sum[n][w] = sum; red_amax[n][w] = amax; }
    }
    __syncthreads();

    // ---- Phase 2b: normalize, quantize, pack to PhT ----
    {
      const float4 rs = *(const float4*)&red_sum[n][0];
      const float4 ra = *(const float4*)&red_amax[n][0];
      float denom = (rs.x + rs.y) + (rs.z + rs.w);
      denom = __fadd_rn(denom, 1e-9f);
      const float rden = 1.0f / denom;
      const float am = fmaxf(fmaxf(ra.x, ra.y), fmaxf(ra.z, ra.w));
      float ps = (am * rden) / 127.0f;
      if (ps == 0.f) ps = 1.f;
      const float rps = 1.0f / ps;
      if (w == 0 && quad == 0) psa[n] = ps;
      #pragma unroll
      for (int t = 0; t < 8; ++t) {
        half4v hq;
        #pragma unroll
        for (int r = 0; r < 4; ++r) {
          const float p = s26[t][r] * rden;
          const float qf = fminf(fmaxf(rintf(p * rps), -127.f), 127.f);
          hq[r] = (_Float16)qf;
        }
        *(half4v*)&PhT[n * PSTR + (t * 4 + w) * 16 + quad * 4] = hq;
      }
    }
    __syncthreads();

    // ---- Phase 3: PV via f16 MFMA, coalesced V (k-chunked layout) ----
    {
      v4f acc0 = {0.f, 0.f, 0.f, 0.f};
      const _Float16* vbase = vt2 + ((size_t)hb * 16 * 64 + (w * 16 + n)) * 32 + quad * 8;
      const _Float16* p0 = &PhT[n * PSTR + quad * 8];
      #pragma unroll 4
      for (int kt = 0; kt < 16; ++kt) {
        const half8 bf = *(const half8*)(vbase + kt * 2048);
        acc0 = __builtin_amdgcn_mfma_f32_16x16x32_f16(*(const half8*)(p0 + kt * 32), bf, acc0, 0, 0, 0);
      }
      #pragma unroll
      for (int r = 0; r < 4; ++r) {
        const int row = quad * 4 + r;
        ctx[((size_t)bz * SEQ + qb + row) * HID + (size_t)hh * HDIM + w * 16 + n] =
            acc0[r] * psa[row];
      }
    }
    // No barrier needed here: next iteration's phase-1 barrier orders
    // PhT/psa reads (this phase 3) before the next phase-2b overwrite.
  }
}

// --------------------------------------------------------------------------
extern "C" void kernel_launch(void* const* d_in, const int* in_sizes, int n_in,
                              void* d_out, int out_size, void* d_ws, size_t ws_size,
                              hipStream_t stream) {
  (void)in_sizes; (void)n_in; (void)out_size; (void)ws_size;
  const float* hs = (const float*)d_in[0];
  const float* Wq = (const float*)d_in[1];
  const float* bq = (const float*)d_in[2];
  const float* Wk = (const float*)d_in[3];
  const float* bk = (const float*)d_in[4];
  const float* Wv = (const float*)d_in[5];
  const float* bv = (const float*)d_in[6];
  const float* Wo = (const float*)d_in[7];
  const float* bo = (const float*)d_in[8];
  float* out = (float*)d_out;

  char* ws = (char*)d_ws;
  size_t off = 0;
  auto alloc = [&](size_t bytes) -> char* {
    char* p = ws + off;
    off += (bytes + 255) & ~(size_t)255;
    return p;
  };
  signed char* qx  = (signed char*)alloc((size_t)R_TOT * HID);
  float*       sx  = (float*)alloc((size_t)R_TOT * 4);
  signed char* qwq = (signed char*)alloc((size_t)HID * HID);
  signed char* qwk = (signed char*)alloc((size_t)HID * HID);
  signed char* qwv = (signed char*)alloc((size_t)HID * HID);
  signed char* qwo = (signed char*)alloc((size_t)HID * HID);
  float*       swq = (float*)alloc((size_t)HID * 4);
  float*       swk = (float*)alloc((size_t)HID * 4);
  float*       swv = (float*)alloc((size_t)HID * 4);
  float*       swo = (float*)alloc((size_t)HID * 4);
  signed char* qqd = (signed char*)alloc((size_t)R_TOT * HID);
  float*       qqs = (float*)alloc((size_t)BATCH * NHEAD * SEQ * 4);
  signed char* qkd = (signed char*)alloc((size_t)R_TOT * HID);
  float*       qks = (float*)alloc((size_t)BATCH * NHEAD * SEQ * 4);
  float*       ctx = (float*)alloc((size_t)R_TOT * HID * 4);
  _Float16*    vt2 = (_Float16*)alloc((size_t)BATCH * NHEAD * HDIM * SEQ * 2);
  // alias: qx/sx are dead after the QKV projections
  signed char* qc  = qx;
  float*       scs = sx;

  quant_all<<<R_TOT + 4 * HID, 256, 0, stream>>>(
      hs, Wq, Wk, Wv, Wo, qx, sx,
      qwq, qwk, qwv, qwo, swq, swk, swv, swo);

  proj_qkv<<<dim3(R_TOT / 128, HID / 64, 3), 256, 0, stream>>>(
      qx, sx, qwq, swq, bq, qqd, qqs,
      qwk, swk, bk, qkd, qks,
      qwv, swv, bv, vt2);

  attn_kernel<<<dim3(SEQ / 32, NHEAD, BATCH), 256, 0, stream>>>(
      qqd, qqs, qkd, qks, vt2, ctx, g_pla);

  quant_rows<<<R_TOT, 256, 0, stream>>>(ctx, HID, qc, scs);
  proj_out<<<dim3(R_TOT / 128, HID / 64), 256, 0, stream>>>(
      qc, scs, qwo, swo, bo, out);
}

// Round 10
// 178.109 us; speedup vs baseline: 1.5609x; 1.5609x over previous
//
#include <hip/hip_runtime.h>
#include <cmath>

#define R_TOT 4096   // B*S rows
#define HID   768
#define NHEAD 12
#define HDIM  64
#define SEQ   512
#define BATCH 8

typedef int   v4i  __attribute__((ext_vector_type(4)));
typedef float v4f  __attribute__((ext_vector_type(4)));
typedef _Float16 half8 __attribute__((ext_vector_type(8)));
typedef _Float16 half4v __attribute__((ext_vector_type(4)));

// ---------------- PLA coefficients (host, replicates np.polyfit in f64) ----
struct PlaConsts { float m[12]; float c[12]; float b[13]; };

static PlaConsts build_pla() {
  PlaConsts pc;
  const int NPTS = 1001;
  static double xs[NPTS], ys[NPTS];
  const double step = 10.0 / 1000.0;
  for (int j = 0; j < NPTS; ++j) xs[j] = (double)j * step + (-10.0);
  xs[NPTS - 1] = 0.0;
  for (int j = 0; j < NPTS; ++j) ys[j] = std::exp(xs[j]);
  double bnd[13];
  const double step2 = 10.0 / 12.0;
  for (int k = 0; k < 13; ++k) bnd[k] = (double)k * step2 + (-10.0);
  bnd[12] = 0.0;
  for (int i = 0; i < 12; ++i) {
    const double a = bnd[i], bb = bnd[i + 1];
    double sx = 0, sy = 0; int n = 0;
    for (int j = 0; j < NPTS; ++j)
      if (xs[j] >= a && xs[j] <= bb) { sx += xs[j]; sy += ys[j]; ++n; }
    const double xm = sx / n, ym = sy / n;
    double sxx = 0, sxy = 0;
    for (int j = 0; j < NPTS; ++j)
      if (xs[j] >= a && xs[j] <= bb) {
        const double dx = xs[j] - xm;
        sxx += dx * dx; sxy += dx * (ys[j] - ym);
      }
    const double m = sxy / sxx;
    pc.m[i] = (float)m;
    pc.c[i] = (float)(ym - m * xm);
  }
  for (int k = 0; k < 13; ++k) pc.b[k] = (float)bnd[k];
  return pc;
}
static const PlaConsts g_pla = build_pla();

// ---------------- per-row abs-max int8 quantization -----------------------
__device__ __forceinline__ void quant_row_body(const float* __restrict__ x,
                                               signed char* __restrict__ qrow,
                                               float* __restrict__ srow,
                                               int ncols) {
  float m = 0.f;
  for (int c = threadIdx.x; c < ncols; c += 256)
    m = fmaxf(m, fabsf(x[c]));
  #pragma unroll
  for (int off = 32; off; off >>= 1) m = fmaxf(m, __shfl_xor(m, off));
  __shared__ float red[4];
  const int lane = threadIdx.x & 63, wv = threadIdx.x >> 6;
  if (lane == 0) red[wv] = m;
  __syncthreads();
  if (threadIdx.x == 0) {
    float mm = fmaxf(fmaxf(red[0], red[1]), fmaxf(red[2], red[3]));
    float s = mm / 127.0f;
    if (s == 0.f) s = 1.f;
    red[0] = s;
    *srow = s;
  }
  __syncthreads();
  const float s = red[0];
  for (int c = threadIdx.x; c < ncols; c += 256) {
    float q = rintf(x[c] / s);
    q = fminf(fmaxf(q, -127.f), 127.f);
    qrow[c] = (signed char)(int)q;
  }
}

__global__ __launch_bounds__(256)
void quant_rows(const float* __restrict__ src, int ncols,
                signed char* __restrict__ qout, float* __restrict__ sout) {
  const int row = blockIdx.x;
  quant_row_body(src + (size_t)row * ncols, qout + (size_t)row * ncols,
                 sout + row, ncols);
}

// hidden states (4096 rows) + 4 weight matrices (4x768 rows) in ONE launch
__global__ __launch_bounds__(256)
void quant_all(const float* hs, const float* w0, const float* w1,
               const float* w2, const float* w3,
               signed char* qx, float* sx,
               signed char* q0, signed char* q1, signed char* q2, signed char* q3,
               float* s0, float* s1, float* s2, float* s3) {
  const int bid = blockIdx.x;
  const float* src; signed char* qo; float* so; int row;
  if (bid < R_TOT)            { src = hs; qo = qx; so = sx; row = bid; }
  else if (bid < R_TOT + 768) { src = w0; qo = q0; so = s0; row = bid - R_TOT; }
  else if (bid < R_TOT + 1536){ src = w1; qo = q1; so = s1; row = bid - R_TOT - 768; }
  else if (bid < R_TOT + 2304){ src = w2; qo = q2; so = s2; row = bid - R_TOT - 1536; }
  else                        { src = w3; qo = q3; so = s3; row = bid - R_TOT - 2304; }
  quant_row_body(src + (size_t)row * HID, qo + (size_t)row * HID, so + row, HID);
}

// ---------------- int8 MFMA GEMM body: 128x64 tile, BK=128 -----------------
// mode 0: fp32 dense out; mode 1: per-head int8 (bhsd) + scales;
// mode 2: V path -> fp16 k-chunked transposed vt2[hb][k>>5][d][k&31]
__device__ __forceinline__
void proj_body(int mode,
               const signed char* __restrict__ qx, const float* __restrict__ sx,
               const signed char* __restrict__ qw, const float* __restrict__ sw,
               const float* __restrict__ bias,
               signed char* __restrict__ qo, float* __restrict__ so,
               _Float16* __restrict__ vt, float* __restrict__ fo,
               signed char* Al, signed char* Bl) {
  const int tid = threadIdx.x;
  const int w = tid >> 6, lane = tid & 63;
  const int n = lane & 15, quad = lane >> 4;
  const int row0 = blockIdx.x * 128, col0 = blockIdx.y * 64;
  const int ar = tid >> 1, ac = (tid & 1) * 64;   // A: 1 row, 64B contiguous
  const int br = tid >> 2, bc = (tid & 3) * 32;   // B: 1 row, 32B contiguous
  v4i acc[2][4];
  #pragma unroll
  for (int s = 0; s < 2; ++s)
    #pragma unroll
    for (int j = 0; j < 4; ++j) acc[s][j] = (v4i){0, 0, 0, 0};
  for (int k0 = 0; k0 < HID; k0 += 128) {
    const signed char* ap = qx + (size_t)(row0 + ar) * HID + k0 + ac;
    const int4 a0 = *(const int4*)(ap);
    const int4 a1 = *(const int4*)(ap + 16);
    const int4 a2 = *(const int4*)(ap + 32);
    const int4 a3 = *(const int4*)(ap + 48);
    const signed char* bp = qw + (size_t)(col0 + br) * HID + k0 + bc;
    const int4 b0 = *(const int4*)(bp);
    const int4 b1 = *(const int4*)(bp + 16);
    if (k0) __syncthreads();
    *(int4*)&Al[ar * 144 + ac]      = a0;
    *(int4*)&Al[ar * 144 + ac + 16] = a1;
    *(int4*)&Al[ar * 144 + ac + 32] = a2;
    *(int4*)&Al[ar * 144 + ac + 48] = a3;
    *(int4*)&Bl[br * 144 + bc]      = b0;
    *(int4*)&Bl[br * 144 + bc + 16] = b1;
    __syncthreads();
    #pragma unroll
    for (int ks = 0; ks < 128; ks += 64) {
      const v4i af0 = *(const v4i*)&Al[(w * 16 + n) * 144 + ks + quad * 16];
      const v4i af1 = *(const v4i*)&Al[(64 + w * 16 + n) * 144 + ks + quad * 16];
      #pragma unroll
      for (int j = 0; j < 4; ++j) {
        const v4i bf = *(const v4i*)&Bl[(j * 16 + n) * 144 + ks + quad * 16];
        acc[0][j] = __builtin_amdgcn_mfma_i32_16x16x64_i8(af0, bf, acc[0][j], 0, 0, 0);
        acc[1][j] = __builtin_amdgcn_mfma_i32_16x16x64_i8(af1, bf, acc[1][j], 0, 0, 0);
      }
    }
  }
  float swc4[4], bc4[4];
  #pragma unroll
  for (int j = 0; j < 4; ++j) {
    swc4[j] = sw[col0 + j * 16 + n];
    bc4[j] = bias[col0 + j * 16 + n];
  }
  #pragma unroll
  for (int s = 0; s < 2; ++s) {
    const int mrow = s * 64 + w * 16 + quad * 4;
    float sxr[4];
    #pragma unroll
    for (int r = 0; r < 4; ++r) sxr[r] = sx[row0 + mrow + r];
    float vals[4][4];  // [j][r]
    #pragma unroll
    for (int j = 0; j < 4; ++j)
      #pragma unroll
      for (int r = 0; r < 4; ++r)
        vals[j][r] = (float)acc[s][j][r] * (sxr[r] * swc4[j]) + bc4[j];
    if (mode == 1) {
      const int h = blockIdx.y;
      #pragma unroll
      for (int r = 0; r < 4; ++r) {
        float m = 0.f;
        #pragma unroll
        for (int j = 0; j < 4; ++j) m = fmaxf(m, fabsf(vals[j][r]));
        #pragma unroll
        for (int off = 1; off < 16; off <<= 1) m = fmaxf(m, __shfl_xor(m, off));
        float sq = m / 127.0f;
        if (sq == 0.f) sq = 1.f;
        const int grow = row0 + mrow + r;
        const int bidx = grow >> 9, sidx = grow & 511;
        const size_t rowidx = ((size_t)bidx * NHEAD + h) * SEQ + sidx;
        #pragma unroll
        for (int j = 0; j < 4; ++j) {
          float q = fminf(fmaxf(rintf(vals[j][r] / sq), -127.f), 127.f);
          qo[rowidx * HDIM + j * 16 + n] = (signed char)(int)q;
        }
        if (n == 0) so[rowidx] = sq;
      }
    } else if (mode == 2) {
      const int h = blockIdx.y;
      float srow[4];
      #pragma unroll
      for (int r = 0; r < 4; ++r) {
        float m = 0.f;
        #pragma unroll
        for (int j = 0; j < 4; ++j) m = fmaxf(m, fabsf(vals[j][r]));
        #pragma unroll
        for (int off = 1; off < 16; off <<= 1) m = fmaxf(m, __shfl_xor(m, off));
        float sq = m / 127.0f;
        if (sq == 0.f) sq = 1.f;
        srow[r] = sq;
      }
      const int grow0 = row0 + mrow;         // 4 consecutive k, same batch
      const int bidx = grow0 >> 9, sidx = grow0 & 511;
      const int kb = sidx >> 5, ko = sidx & 31;
      const size_t hbv = (size_t)bidx * NHEAD + h;
      #pragma unroll
      for (int j = 0; j < 4; ++j) {
        half4v hv;
        #pragma unroll
        for (int r = 0; r < 4; ++r) {
          float q = fminf(fmaxf(rintf(vals[j][r] / srow[r]), -127.f), 127.f);
          hv[r] = (_Float16)(q * srow[r]);
        }
        *(half4v*)(vt + ((hbv * 16 + kb) * 64 + j * 16 + n) * 32 + ko) = hv;
      }
    } else {
      #pragma unroll
      for (int r = 0; r < 4; ++r) {
        const size_t base = (size_t)(row0 + mrow + r) * HID + col0;
        #pragma unroll
        for (int j = 0; j < 4; ++j)
          fo[base + j * 16 + n] = vals[j][r];
      }
    }
  }
}

// fused Q/K/V projections: blockIdx.z selects weight/output
__global__ __launch_bounds__(256)
void proj_qkv(const signed char* __restrict__ qx, const float* __restrict__ sx,
              const signed char* qwq, const float* swq, const float* bq,
              signed char* qqd, float* qqs,
              const signed char* qwk, const float* swk, const float* bk,
              signed char* qkd, float* qks,
              const signed char* qwv, const float* swv, const float* bv,
              _Float16* vt2) {
  __shared__ __align__(16) signed char Al[128 * 144];
  __shared__ __align__(16) signed char Bl[64 * 144];
  if (blockIdx.z == 0)
    proj_body(1, qx, sx, qwq, swq, bq, qqd, qqs, nullptr, nullptr, Al, Bl);
  else if (blockIdx.z == 1)
    proj_body(1, qx, sx, qwk, swk, bk, qkd, qks, nullptr, nullptr, Al, Bl);
  else
    proj_body(2, qx, sx, qwv, swv, bv, nullptr, nullptr, vt2, nullptr, Al, Bl);
}

__global__ __launch_bounds__(256)
void proj_out(const signed char* __restrict__ qx, const float* __restrict__ sx,
              const signed char* qw, const float* sw, const float* bias,
              float* fo) {
  __shared__ __align__(16) signed char Al[128 * 144];
  __shared__ __align__(16) signed char Bl[64 * 144];
  proj_body(0, qx, sx, qw, sw, bias, nullptr, nullptr, nullptr, fo, Al, Bl);
}

// ---------------- fused attention: 32 q-rows/block, per-tile loop ----------
// One 16-row tile at a time through a single PhT buffer: LDS 17.7 KB.
// NOTE: plain __launch_bounds__(256) — R9's (256,6) min-waves hint forced
// VGPR to 40 and spilled s26 to scratch (FETCH/WRITE_SIZE ballooned to
// 279 MB, attn 145us). Natural allocation fits in ~64 VGPR, no spill.
#define PSTR 520  // PhT row stride in halves (16B-aligned rows)
__global__ __launch_bounds__(256)
void attn_kernel(const signed char* __restrict__ qq, const float* __restrict__ qss,
                 const signed char* __restrict__ qk, const float* __restrict__ kss,
                 const _Float16* __restrict__ vt2,
                 float* __restrict__ ctx, const PlaConsts pc) {
  __shared__ __align__(16) _Float16 PhT[16 * PSTR];  // quantized probs (1 tile)
  __shared__ __align__(16) float red_max[16][4];
  __shared__ __align__(16) float red_sum[16][4];
  __shared__ __align__(16) float red_amax[16][4];
  __shared__ float psa[16];
  __shared__ __align__(8) float pb2[12][2];
  __shared__ __align__(8) float pmc[12][2];

  const int tid = threadIdx.x;
  const int q0 = blockIdx.x * 32;
  const int hh = blockIdx.y, bz = blockIdx.z;
  const size_t hb = (size_t)bz * NHEAD + hh;
  const signed char* qkh = qk + hb * SEQ * HDIM;
  const float* ksp = kss + hb * SEQ;

  if (tid < 12) {
    pb2[tid][0] = pc.b[tid]; pb2[tid][1] = pc.b[tid + 1];
    pmc[tid][0] = pc.m[tid]; pmc[tid][1] = pc.c[tid];
  }

  const int w = tid >> 6, lane = tid & 63;
  const int n = lane & 15, quad = lane >> 4;

  for (int tau = 0; tau < 2; ++tau) {
    const int qb = q0 + tau * 16;
    const signed char* qqh = qq + (hb * SEQ + qb) * HDIM;

    // ---- Phase 1: S^T via i8 MFMA (A=K rows, B=Q rows) ----
    float s26[8][4];
    {
      const v4i qf0 = *(const v4i*)(qqh + (size_t)n * HDIM + quad * 16);
      const float qs0 = (qss[hb * SEQ + qb + n] * 0.125f) * 67108864.0f;
      float vmax0 = -3.0e38f;
      #pragma unroll
      for (int t = 0; t < 8; ++t) {
        const int kc0 = (t * 4 + w) * 16;
        const v4i kfrag = *(const v4i*)(qkh + (size_t)(kc0 + n) * HDIM + quad * 16);
        const float4 ks4 = *(const float4*)(ksp + kc0 + quad * 4);
        v4i zero = {};
        const v4i a0 = __builtin_amdgcn_mfma_i32_16x16x64_i8(kfrag, qf0, zero, 0, 0, 0);
        const float ks[4] = {ks4.x, ks4.y, ks4.z, ks4.w};
        #pragma unroll
        for (int r = 0; r < 4; ++r) {
          const float v0 = (float)a0[r] * (qs0 * ks[r]);
          s26[t][r] = v0; vmax0 = fmaxf(vmax0, v0);
        }
      }
      vmax0 = fmaxf(vmax0, __shfl_xor(vmax0, 16));
      vmax0 = fmaxf(vmax0, __shfl_xor(vmax0, 32));
      if (quad == 0) red_max[n][w] = vmax0;
    }
    __syncthreads();

    // ---- Phase 2a: PLA exp (one row per lane), partial sums ----
    {
      const float4 rm = *(const float4*)&red_max[n][0];
      const float mx26 = fmaxf(fmaxf(rm.x, rm.y), fmaxf(rm.z, rm.w));
      float sum = 0.f, amax = 0.f;
      #pragma unroll
      for (int t = 0; t < 8; ++t) {
        #pragma unroll
        for (int r = 0; r < 4; ++r) {
          float sh = s26[t][r] - mx26;            // == (s-mx)*2^26 exactly
          sh = fmaxf(sh, -671088640.0f);          // clamp at -10*2^26
          const float tq = rintf(sh);
          const float xc = tq * 1.4901161193847656e-08f;  // *2^-26 (exact)
          int g = (int)floorf((xc + 10.0f) * 1.2f);
          g = g < 0 ? 0 : (g > 11 ? 11 : g);
          const float2 bb = *(const float2*)&pb2[g][0];
          if (xc < bb.x) --g;
          else if (xc >= bb.y) ++g;
          g = g < 0 ? 0 : (g > 11 ? 11 : g);
          const float2 mc = *(const float2*)&pmc[g][0];
          const float e = __fadd_rn(__fmul_rn(mc.x, xc), mc.y);
          s26[t][r] = e;
          sum += e;
          amax = fmaxf(amax, fabsf(e));
        }
      }
      sum += __shfl_xor(sum, 16);
      sum += __shfl_xor(sum, 32);
      amax = fmaxf(amax, __shfl_xor(amax, 16));
      amax = fmaxf(amax, __shfl_xor(amax, 32));
      if (quad == 0) { red_sum[n][w] = sum; red_amax[n][w] = amax; }
    }
    __syncthreads();

    // ---- Phase 2b: normalize, quantize, pack to PhT ----
    {
      const float4 rs = *(const float4*)&red_sum[n][0];
      const float4 ra = *(const float4*)&red_amax[n][0];
      float denom = (rs.x + rs.y) + (rs.z + rs.w);
      denom = __fadd_rn(denom, 1e-9f);
      const float rden = 1.0f / denom;
      const float am = fmaxf(fmaxf(ra.x, ra.y), fmaxf(ra.z, ra.w));
      float ps = (am * rden) / 127.0f;
      if (ps == 0.f) ps = 1.f;
      const float rps = 1.0f / ps;
      if (w == 0 && quad == 0) psa[n] = ps;
      #pragma unroll
      for (int t = 0; t < 8; ++t) {
        half4v hq;
        #pragma unroll
        for (int r = 0; r < 4; ++r) {
          const float p = s26[t][r] * rden;
          const float qf = fminf(fmaxf(rintf(p * rps), -127.f), 127.f);
          hq[r] = (_Float16)qf;
        }
        *(half4v*)&PhT[n * PSTR + (t * 4 + w) * 16 + quad * 4] = hq;
      }
    }
    __syncthreads();

    // ---- Phase 3: PV via f16 MFMA, coalesced V (k-chunked layout) ----
    {
      v4f acc0 = {0.f, 0.f, 0.f, 0.f};
      const _Float16* vbase = vt2 + ((size_t)hb * 16 * 64 + (w * 16 + n)) * 32 + quad * 8;
      const _Float16* p0 = &PhT[n * PSTR + quad * 8];
      #pragma unroll 4
      for (int kt = 0; kt < 16; ++kt) {
        const half8 bf = *(const half8*)(vbase + kt * 2048);
        acc0 = __builtin_amdgcn_mfma_f32_16x16x32_f16(*(const half8*)(p0 + kt * 32), bf, acc0, 0, 0, 0);
      }
      #pragma unroll
      for (int r = 0; r < 4; ++r) {
        const int row = quad * 4 + r;
        ctx[((size_t)bz * SEQ + qb + row) * HID + (size_t)hh * HDIM + w * 16 + n] =
            acc0[r] * psa[row];
      }
    }
    // No barrier needed here: next iteration's phase-1 barrier orders
    // PhT/psa reads (this phase 3) before the next phase-2b overwrite.
  }
}

// --------------------------------------------------------------------------
extern "C" void kernel_launch(void* const* d_in, const int* in_sizes, int n_in,
                              void* d_out, int out_size, void* d_ws, size_t ws_size,
                              hipStream_t stream) {
  (void)in_sizes; (void)n_in; (void)out_size; (void)ws_size;
  const float* hs = (const float*)d_in[0];
  const float* Wq = (const float*)d_in[1];
  const float* bq = (const float*)d_in[2];
  const float* Wk = (const float*)d_in[3];
  const float* bk = (const float*)d_in[4];
  const float* Wv = (const float*)d_in[5];
  const float* bv = (const float*)d_in[6];
  const float* Wo = (const float*)d_in[7];
  const float* bo = (const float*)d_in[8];
  float* out = (float*)d_out;

  char* ws = (char*)d_ws;
  size_t off = 0;
  auto alloc = [&](size_t bytes) -> char* {
    char* p = ws + off;
    off += (bytes + 255) & ~(size_t)255;
    return p;
  };
  signed char* qx  = (signed char*)alloc((size_t)R_TOT * HID);
  float*       sx  = (float*)alloc((size_t)R_TOT * 4);
  signed char* qwq = (signed char*)alloc((size_t)HID * HID);
  signed char* qwk = (signed char*)alloc((size_t)HID * HID);
  signed char* qwv = (signed char*)alloc((size_t)HID * HID);
  signed char* qwo = (signed char*)alloc((size_t)HID * HID);
  float*       swq = (float*)alloc((size_t)HID * 4);
  float*       swk = (float*)alloc((size_t)HID * 4);
  float*       swv = (float*)alloc((size_t)HID * 4);
  float*       swo = (float*)alloc((size_t)HID * 4);
  signed char* qqd = (signed char*)alloc((size_t)R_TOT * HID);
  float*       qqs = (float*)alloc((size_t)BATCH * NHEAD * SEQ * 4);
  signed char* qkd = (signed char*)alloc((size_t)R_TOT * HID);
  float*       qks = (float*)alloc((size_t)BATCH * NHEAD * SEQ * 4);
  float*       ctx = (float*)alloc((size_t)R_TOT * HID * 4);
  _Float16*    vt2 = (_Float16*)alloc((size_t)BATCH * NHEAD * HDIM * SEQ * 2);
  // alias: qx/sx are dead after the QKV projections
  signed char* qc  = qx;
  float*       scs = sx;

  quant_all<<<R_TOT + 4 * HID, 256, 0, stream>>>(
      hs, Wq, Wk, Wv, Wo, qx, sx,
      qwq, qwk, qwv, qwo, swq, swk, swv, swo);

  proj_qkv<<<dim3(R_TOT / 128, HID / 64, 3), 256, 0, stream>>>(
      qx, sx, qwq, swq, bq, qqd, qqs,
      qwk, swk, bk, qkd, qks,
      qwv, swv, bv, vt2);

  attn_kernel<<<dim3(SEQ / 32, NHEAD, BATCH), 256, 0, stream>>>(
      qqd, qqs, qkd, qks, vt2, ctx, g_pla);

  quant_rows<<<R_TOT, 256, 0, stream>>>(ctx, HID, qc, scs);
  proj_out<<<dim3(R_TOT / 128, HID / 64), 256, 0, stream>>>(
      qc, scs, qwo, swo, bo, out);
}

// Round 11
// 162.702 us; speedup vs baseline: 1.7088x; 1.0947x over previous
//
#include <hip/hip_runtime.h>
#include <cmath>

#define R_TOT 4096   // B*S rows
#define HID   768
#define NHEAD 12
#define HDIM  64
#define SEQ   512
#define BATCH 8

typedef int   v4i  __attribute__((ext_vector_type(4)));
typedef float v4f  __attribute__((ext_vector_type(4)));
typedef _Float16 half8 __attribute__((ext_vector_type(8)));
typedef _Float16 half4v __attribute__((ext_vector_type(4)));

// ---------------- PLA coefficients (host, replicates np.polyfit in f64) ----
struct PlaConsts { float m[12]; float c[12]; float b[13]; };

static PlaConsts build_pla() {
  PlaConsts pc;
  const int NPTS = 1001;
  static double xs[NPTS], ys[NPTS];
  const double step = 10.0 / 1000.0;
  for (int j = 0; j < NPTS; ++j) xs[j] = (double)j * step + (-10.0);
  xs[NPTS - 1] = 0.0;
  for (int j = 0; j < NPTS; ++j) ys[j] = std::exp(xs[j]);
  double bnd[13];
  const double step2 = 10.0 / 12.0;
  for (int k = 0; k < 13; ++k) bnd[k] = (double)k * step2 + (-10.0);
  bnd[12] = 0.0;
  for (int i = 0; i < 12; ++i) {
    const double a = bnd[i], bb = bnd[i + 1];
    double sx = 0, sy = 0; int n = 0;
    for (int j = 0; j < NPTS; ++j)
      if (xs[j] >= a && xs[j] <= bb) { sx += xs[j]; sy += ys[j]; ++n; }
    const double xm = sx / n, ym = sy / n;
    double sxx = 0, sxy = 0;
    for (int j = 0; j < NPTS; ++j)
      if (xs[j] >= a && xs[j] <= bb) {
        const double dx = xs[j] - xm;
        sxx += dx * dx; sxy += dx * (ys[j] - ym);
      }
    const double m = sxy / sxx;
    pc.m[i] = (float)m;
    pc.c[i] = (float)(ym - m * xm);
  }
  for (int k = 0; k < 13; ++k) pc.b[k] = (float)bnd[k];
  return pc;
}
static const PlaConsts g_pla = build_pla();

// ---------------- per-row abs-max int8 quantization -----------------------
__device__ __forceinline__ void quant_row_body(const float* __restrict__ x,
                                               signed char* __restrict__ qrow,
                                               float* __restrict__ srow,
                                               int ncols) {
  float m = 0.f;
  for (int c = threadIdx.x; c < ncols; c += 256)
    m = fmaxf(m, fabsf(x[c]));
  #pragma unroll
  for (int off = 32; off; off >>= 1) m = fmaxf(m, __shfl_xor(m, off));
  __shared__ float red[4];
  const int lane = threadIdx.x & 63, wv = threadIdx.x >> 6;
  if (lane == 0) red[wv] = m;
  __syncthreads();
  if (threadIdx.x == 0) {
    float mm = fmaxf(fmaxf(red[0], red[1]), fmaxf(red[2], red[3]));
    float s = mm / 127.0f;
    if (s == 0.f) s = 1.f;
    red[0] = s;
    *srow = s;
  }
  __syncthreads();
  const float s = red[0];
  for (int c = threadIdx.x; c < ncols; c += 256) {
    float q = rintf(x[c] / s);
    q = fminf(fmaxf(q, -127.f), 127.f);
    qrow[c] = (signed char)(int)q;
  }
}

__global__ __launch_bounds__(256)
void quant_rows(const float* __restrict__ src, int ncols,
                signed char* __restrict__ qout, float* __restrict__ sout) {
  const int row = blockIdx.x;
  quant_row_body(src + (size_t)row * ncols, qout + (size_t)row * ncols,
                 sout + row, ncols);
}

// hidden states (4096 rows) + 4 weight matrices (4x768 rows) in ONE launch
__global__ __launch_bounds__(256)
void quant_all(const float* hs, const float* w0, const float* w1,
               const float* w2, const float* w3,
               signed char* qx, float* sx,
               signed char* q0, signed char* q1, signed char* q2, signed char* q3,
               float* s0, float* s1, float* s2, float* s3) {
  const int bid = blockIdx.x;
  const float* src; signed char* qo; float* so; int row;
  if (bid < R_TOT)            { src = hs; qo = qx; so = sx; row = bid; }
  else if (bid < R_TOT + 768) { src = w0; qo = q0; so = s0; row = bid - R_TOT; }
  else if (bid < R_TOT + 1536){ src = w1; qo = q1; so = s1; row = bid - R_TOT - 768; }
  else if (bid < R_TOT + 2304){ src = w2; qo = q2; so = s2; row = bid - R_TOT - 1536; }
  else                        { src = w3; qo = q3; so = s3; row = bid - R_TOT - 2304; }
  quant_row_body(src + (size_t)row * HID, qo + (size_t)row * HID, so + row, HID);
}

// ---------------- int8 MFMA GEMM body: 128x64 tile, BK=128 -----------------
// mode 0: fp32 dense out; mode 1: per-head int8 (bhsd) + scales;
// mode 2: V path -> fp16 k-chunked transposed vt2[hb][k>>5][d][k&31]
__device__ __forceinline__
void proj_body(int mode,
               const signed char* __restrict__ qx, const float* __restrict__ sx,
               const signed char* __restrict__ qw, const float* __restrict__ sw,
               const float* __restrict__ bias,
               signed char* __restrict__ qo, float* __restrict__ so,
               _Float16* __restrict__ vt, float* __restrict__ fo,
               signed char* Al, signed char* Bl) {
  const int tid = threadIdx.x;
  const int w = tid >> 6, lane = tid & 63;
  const int n = lane & 15, quad = lane >> 4;
  const int row0 = blockIdx.x * 128, col0 = blockIdx.y * 64;
  const int ar = tid >> 1, ac = (tid & 1) * 64;   // A: 1 row, 64B contiguous
  const int br = tid >> 2, bc = (tid & 3) * 32;   // B: 1 row, 32B contiguous
  v4i acc[2][4];
  #pragma unroll
  for (int s = 0; s < 2; ++s)
    #pragma unroll
    for (int j = 0; j < 4; ++j) acc[s][j] = (v4i){0, 0, 0, 0};
  for (int k0 = 0; k0 < HID; k0 += 128) {
    const signed char* ap = qx + (size_t)(row0 + ar) * HID + k0 + ac;
    const int4 a0 = *(const int4*)(ap);
    const int4 a1 = *(const int4*)(ap + 16);
    const int4 a2 = *(const int4*)(ap + 32);
    const int4 a3 = *(const int4*)(ap + 48);
    const signed char* bp = qw + (size_t)(col0 + br) * HID + k0 + bc;
    const int4 b0 = *(const int4*)(bp);
    const int4 b1 = *(const int4*)(bp + 16);
    if (k0) __syncthreads();
    *(int4*)&Al[ar * 144 + ac]      = a0;
    *(int4*)&Al[ar * 144 + ac + 16] = a1;
    *(int4*)&Al[ar * 144 + ac + 32] = a2;
    *(int4*)&Al[ar * 144 + ac + 48] = a3;
    *(int4*)&Bl[br * 144 + bc]      = b0;
    *(int4*)&Bl[br * 144 + bc + 16] = b1;
    __syncthreads();
    #pragma unroll
    for (int ks = 0; ks < 128; ks += 64) {
      const v4i af0 = *(const v4i*)&Al[(w * 16 + n) * 144 + ks + quad * 16];
      const v4i af1 = *(const v4i*)&Al[(64 + w * 16 + n) * 144 + ks + quad * 16];
      #pragma unroll
      for (int j = 0; j < 4; ++j) {
        const v4i bf = *(const v4i*)&Bl[(j * 16 + n) * 144 + ks + quad * 16];
        acc[0][j] = __builtin_amdgcn_mfma_i32_16x16x64_i8(af0, bf, acc[0][j], 0, 0, 0);
        acc[1][j] = __builtin_amdgcn_mfma_i32_16x16x64_i8(af1, bf, acc[1][j], 0, 0, 0);
      }
    }
  }
  float swc4[4], bc4[4];
  #pragma unroll
  for (int j = 0; j < 4; ++j) {
    swc4[j] = sw[col0 + j * 16 + n];
    bc4[j] = bias[col0 + j * 16 + n];
  }
  #pragma unroll
  for (int s = 0; s < 2; ++s) {
    const int mrow = s * 64 + w * 16 + quad * 4;
    float sxr[4];
    #pragma unroll
    for (int r = 0; r < 4; ++r) sxr[r] = sx[row0 + mrow + r];
    float vals[4][4];  // [j][r]
    #pragma unroll
    for (int j = 0; j < 4; ++j)
      #pragma unroll
      for (int r = 0; r < 4; ++r)
        vals[j][r] = (float)acc[s][j][r] * (sxr[r] * swc4[j]) + bc4[j];
    if (mode == 1) {
      const int h = blockIdx.y;
      #pragma unroll
      for (int r = 0; r < 4; ++r) {
        float m = 0.f;
        #pragma unroll
        for (int j = 0; j < 4; ++j) m = fmaxf(m, fabsf(vals[j][r]));
        #pragma unroll
        for (int off = 1; off < 16; off <<= 1) m = fmaxf(m, __shfl_xor(m, off));
        float sq = m / 127.0f;
        if (sq == 0.f) sq = 1.f;
        const int grow = row0 + mrow + r;
        const int bidx = grow >> 9, sidx = grow & 511;
        const size_t rowidx = ((size_t)bidx * NHEAD + h) * SEQ + sidx;
        #pragma unroll
        for (int j = 0; j < 4; ++j) {
          float q = fminf(fmaxf(rintf(vals[j][r] / sq), -127.f), 127.f);
          qo[rowidx * HDIM + j * 16 + n] = (signed char)(int)q;
        }
        if (n == 0) so[rowidx] = sq;
      }
    } else if (mode == 2) {
      const int h = blockIdx.y;
      float srow[4];
      #pragma unroll
      for (int r = 0; r < 4; ++r) {
        float m = 0.f;
        #pragma unroll
        for (int j = 0; j < 4; ++j) m = fmaxf(m, fabsf(vals[j][r]));
        #pragma unroll
        for (int off = 1; off < 16; off <<= 1) m = fmaxf(m, __shfl_xor(m, off));
        float sq = m / 127.0f;
        if (sq == 0.f) sq = 1.f;
        srow[r] = sq;
      }
      const int grow0 = row0 + mrow;         // 4 consecutive k, same batch
      const int bidx = grow0 >> 9, sidx = grow0 & 511;
      const int kb = sidx >> 5, ko = sidx & 31;
      const size_t hbv = (size_t)bidx * NHEAD + h;
      #pragma unroll
      for (int j = 0; j < 4; ++j) {
        half4v hv;
        #pragma unroll
        for (int r = 0; r < 4; ++r) {
          float q = fminf(fmaxf(rintf(vals[j][r] / srow[r]), -127.f), 127.f);
          hv[r] = (_Float16)(q * srow[r]);
        }
        *(half4v*)(vt + ((hbv * 16 + kb) * 64 + j * 16 + n) * 32 + ko) = hv;
      }
    } else {
      #pragma unroll
      for (int r = 0; r < 4; ++r) {
        const size_t base = (size_t)(row0 + mrow + r) * HID + col0;
        #pragma unroll
        for (int j = 0; j < 4; ++j)
          fo[base + j * 16 + n] = vals[j][r];
      }
    }
  }
}

// fused Q/K/V projections: blockIdx.z selects weight/output
__global__ __launch_bounds__(256)
void proj_qkv(const signed char* __restrict__ qx, const float* __restrict__ sx,
              const signed char* qwq, const float* swq, const float* bq,
              signed char* qqd, float* qqs,
              const signed char* qwk, const float* swk, const float* bk,
              signed char* qkd, float* qks,
              const signed char* qwv, const float* swv, const float* bv,
              _Float16* vt2) {
  __shared__ __align__(16) signed char Al[128 * 144];
  __shared__ __align__(16) signed char Bl[64 * 144];
  if (blockIdx.z == 0)
    proj_body(1, qx, sx, qwq, swq, bq, qqd, qqs, nullptr, nullptr, Al, Bl);
  else if (blockIdx.z == 1)
    proj_body(1, qx, sx, qwk, swk, bk, qkd, qks, nullptr, nullptr, Al, Bl);
  else
    proj_body(2, qx, sx, qwv, swv, bv, nullptr, nullptr, vt2, nullptr, Al, Bl);
}

__global__ __launch_bounds__(256)
void proj_out(const signed char* __restrict__ qx, const float* __restrict__ sx,
              const signed char* qw, const float* sw, const float* bias,
              float* fo) {
  __shared__ __align__(16) signed char Al[128 * 144];
  __shared__ __align__(16) signed char Bl[64 * 144];
  proj_body(0, qx, sx, qw, sw, bias, nullptr, nullptr, nullptr, fo, Al, Bl);
}

// ---------------- fused attention: dual-tile compute, single PhT buffer ----
// R8's dual-tile phase1/2a (proven fast) + PhT reuse: 2b(t0)->PV(t0)->2b(t1)
// ->PV(t1) through ONE 16-row buffer. LDS 35.3 -> ~17.9 KB so all 1536
// blocks fit resident (R8 ran ~1.5 dispatch rounds at 4 blocks/CU).
#define PSTR 520  // PhT row stride in halves (16B-aligned rows)
__global__ __launch_bounds__(256)
void attn_kernel(const signed char* __restrict__ qq, const float* __restrict__ qss,
                 const signed char* __restrict__ qk, const float* __restrict__ kss,
                 const _Float16* __restrict__ vt2,
                 float* __restrict__ ctx, const PlaConsts pc) {
  __shared__ __align__(16) _Float16 PhT[16 * PSTR];  // one tile at a time
  __shared__ __align__(16) float red_max[2][16][4];
  __shared__ __align__(16) float red_sum[2][16][4];
  __shared__ __align__(16) float red_amax[2][16][4];
  __shared__ float psa[2][16];
  __shared__ __align__(8) float pb2[12][2];
  __shared__ __align__(8) float pmc[12][2];

  const int tid = threadIdx.x;
  const int q0 = blockIdx.x * 32;
  const int hh = blockIdx.y, bz = blockIdx.z;
  const size_t hb = (size_t)bz * NHEAD + hh;
  const signed char* qqh = qq + (hb * SEQ + q0) * HDIM;
  const signed char* qkh = qk + hb * SEQ * HDIM;
  const float* ksp = kss + hb * SEQ;

  if (tid < 12) {
    pb2[tid][0] = pc.b[tid]; pb2[tid][1] = pc.b[tid + 1];
    pmc[tid][0] = pc.m[tid]; pmc[tid][1] = pc.c[tid];
  }

  const int w = tid >> 6, lane = tid & 63;
  const int n = lane & 15, quad = lane >> 4;

  // ---- Phase 1: S^T via i8 MFMA (A=K rows, B=Q rows), two q-tiles ----
  float s26[2][8][4];
  {
    const v4i qf0 = *(const v4i*)(qqh + (size_t)n * HDIM + quad * 16);
    const v4i qf1 = *(const v4i*)(qqh + (size_t)(16 + n) * HDIM + quad * 16);
    const float qs0 = (qss[hb * SEQ + q0 + n] * 0.125f) * 67108864.0f;
    const float qs1 = (qss[hb * SEQ + q0 + 16 + n] * 0.125f) * 67108864.0f;
    float vmax0 = -3.0e38f, vmax1 = -3.0e38f;
    #pragma unroll
    for (int t = 0; t < 8; ++t) {
      const int kc0 = (t * 4 + w) * 16;
      const v4i kfrag = *(const v4i*)(qkh + (size_t)(kc0 + n) * HDIM + quad * 16);
      const float4 ks4 = *(const float4*)(ksp + kc0 + quad * 4);
      v4i zero = {};
      const v4i a0 = __builtin_amdgcn_mfma_i32_16x16x64_i8(kfrag, qf0, zero, 0, 0, 0);
      const v4i a1 = __builtin_amdgcn_mfma_i32_16x16x64_i8(kfrag, qf1, zero, 0, 0, 0);
      const float ks[4] = {ks4.x, ks4.y, ks4.z, ks4.w};
      #pragma unroll
      for (int r = 0; r < 4; ++r) {
        const float v0 = (float)a0[r] * (qs0 * ks[r]);
        const float v1 = (float)a1[r] * (qs1 * ks[r]);
        s26[0][t][r] = v0; vmax0 = fmaxf(vmax0, v0);
        s26[1][t][r] = v1; vmax1 = fmaxf(vmax1, v1);
      }
    }
    vmax0 = fmaxf(vmax0, __shfl_xor(vmax0, 16));
    vmax0 = fmaxf(vmax0, __shfl_xor(vmax0, 32));
    vmax1 = fmaxf(vmax1, __shfl_xor(vmax1, 16));
    vmax1 = fmaxf(vmax1, __shfl_xor(vmax1, 32));
    if (quad == 0) { red_max[0][n][w] = vmax0; red_max[1][n][w] = vmax1; }
  }
  __syncthreads();

  // ---- Phase 2a: PLA exp (one row per lane per tile), partial sums ----
  #pragma unroll
  for (int tau = 0; tau < 2; ++tau) {
    const float4 rm = *(const float4*)&red_max[tau][n][0];
    const float mx26 = fmaxf(fmaxf(rm.x, rm.y), fmaxf(rm.z, rm.w));
    float sum = 0.f, amax = 0.f;
    #pragma unroll
    for (int t = 0; t < 8; ++t) {
      #pragma unroll
      for (int r = 0; r < 4; ++r) {
        float sh = s26[tau][t][r] - mx26;       // == (s-mx)*2^26 exactly
        sh = fmaxf(sh, -671088640.0f);          // clamp at -10*2^26
        const float tq = rintf(sh);
        const float xc = tq * 1.4901161193847656e-08f;  // *2^-26 (exact)
        int g = (int)floorf((xc + 10.0f) * 1.2f);
        g = g < 0 ? 0 : (g > 11 ? 11 : g);
        const float2 bb = *(const float2*)&pb2[g][0];
        if (xc < bb.x) --g;
        else if (xc >= bb.y) ++g;
        g = g < 0 ? 0 : (g > 11 ? 11 : g);
        const float2 mc = *(const float2*)&pmc[g][0];
        const float e = __fadd_rn(__fmul_rn(mc.x, xc), mc.y);
        s26[tau][t][r] = e;
        sum += e;
        amax = fmaxf(amax, fabsf(e));
      }
    }
    sum += __shfl_xor(sum, 16);
    sum += __shfl_xor(sum, 32);
    amax = fmaxf(amax, __shfl_xor(amax, 16));
    amax = fmaxf(amax, __shfl_xor(amax, 32));
    if (quad == 0) { red_sum[tau][n][w] = sum; red_amax[tau][n][w] = amax; }
  }
  __syncthreads();

  // ---- Phase 2b/3 per tile through the shared PhT buffer ----
  #pragma unroll
  for (int tau = 0; tau < 2; ++tau) {
    // 2b: normalize, quantize, pack to PhT
    {
      const float4 rs = *(const float4*)&red_sum[tau][n][0];
      const float4 ra = *(const float4*)&red_amax[tau][n][0];
      float denom = (rs.x + rs.y) + (rs.z + rs.w);
      denom = __fadd_rn(denom, 1e-9f);
      const float rden = 1.0f / denom;
      const float am = fmaxf(fmaxf(ra.x, ra.y), fmaxf(ra.z, ra.w));
      float ps = (am * rden) / 127.0f;
      if (ps == 0.f) ps = 1.f;
      const float rps = 1.0f / ps;
      if (w == 0 && quad == 0) psa[tau][n] = ps;
      #pragma unroll
      for (int t = 0; t < 8; ++t) {
        half4v hq;
        #pragma unroll
        for (int r = 0; r < 4; ++r) {
          const float p = s26[tau][t][r] * rden;
          const float qf = fminf(fmaxf(rintf(p * rps), -127.f), 127.f);
          hq[r] = (_Float16)qf;
        }
        *(half4v*)&PhT[n * PSTR + (t * 4 + w) * 16 + quad * 4] = hq;
      }
    }
    __syncthreads();
    // Phase 3: PV via f16 MFMA, coalesced V (k-chunked layout)
    {
      v4f acc0 = {0.f, 0.f, 0.f, 0.f};
      const _Float16* vbase = vt2 + ((size_t)hb * 16 * 64 + (w * 16 + n)) * 32 + quad * 8;
      const _Float16* p0 = &PhT[n * PSTR + quad * 8];
      #pragma unroll 4
      for (int kt = 0; kt < 16; ++kt) {
        const half8 bf = *(const half8*)(vbase + kt * 2048);
        acc0 = __builtin_amdgcn_mfma_f32_16x16x32_f16(*(const half8*)(p0 + kt * 32), bf, acc0, 0, 0, 0);
      }
      #pragma unroll
      for (int r = 0; r < 4; ++r) {
        const int row = quad * 4 + r;
        ctx[((size_t)bz * SEQ + q0 + tau * 16 + row) * HID + (size_t)hh * HDIM + w * 16 + n] =
            acc0[r] * psa[tau][row];
      }
    }
    if (tau == 0) __syncthreads();  // PhT write-after-read fence for tile 1
  }
}

// --------------------------------------------------------------------------
extern "C" void kernel_launch(void* const* d_in, const int* in_sizes, int n_in,
                              void* d_out, int out_size, void* d_ws, size_t ws_size,
                              hipStream_t stream) {
  (void)in_sizes; (void)n_in; (void)out_size; (void)ws_size;
  const float* hs = (const float*)d_in[0];
  const float* Wq = (const float*)d_in[1];
  const float* bq = (const float*)d_in[2];
  const float* Wk = (const float*)d_in[3];
  const float* bk = (const float*)d_in[4];
  const float* Wv = (const float*)d_in[5];
  const float* bv = (const float*)d_in[6];
  const float* Wo = (const float*)d_in[7];
  const float* bo = (const float*)d_in[8];
  float* out = (float*)d_out;

  char* ws = (char*)d_ws;
  size_t off = 0;
  auto alloc = [&](size_t bytes) -> char* {
    char* p = ws + off;
    off += (bytes + 255) & ~(size_t)255;
    return p;
  };
  signed char* qx  = (signed char*)alloc((size_t)R_TOT * HID);
  float*       sx  = (float*)alloc((size_t)R_TOT * 4);
  signed char* qwq = (signed char*)alloc((size_t)HID * HID);
  signed char* qwk = (signed char*)alloc((size_t)HID * HID);
  signed char* qwv = (signed char*)alloc((size_t)HID * HID);
  signed char* qwo = (signed char*)alloc((size_t)HID * HID);
  float*       swq = (float*)alloc((size_t)HID * 4);
  float*       swk = (float*)alloc((size_t)HID * 4);
  float*       swv = (float*)alloc((size_t)HID * 4);
  float*       swo = (float*)alloc((size_t)HID * 4);
  signed char* qqd = (signed char*)alloc((size_t)R_TOT * HID);
  float*       qqs = (float*)alloc((size_t)BATCH * NHEAD * SEQ * 4);
  signed char* qkd = (signed char*)alloc((size_t)R_TOT * HID);
  float*       qks = (float*)alloc((size_t)BATCH * NHEAD * SEQ * 4);
  float*       ctx = (float*)alloc((size_t)R_TOT * HID * 4);
  _Float16*    vt2 = (_Float16*)alloc((size_t)BATCH * NHEAD * HDIM * SEQ * 2);
  // alias: qx/sx are dead after the QKV projections
  signed char* qc  = qx;
  float*       scs = sx;

  quant_all<<<R_TOT + 4 * HID, 256, 0, stream>>>(
      hs, Wq, Wk, Wv, Wo, qx, sx,
      qwq, qwk, qwv, qwo, swq, swk, swv, swo);

  proj_qkv<<<dim3(R_TOT / 128, HID / 64, 3), 256, 0, stream>>>(
      qx, sx, qwq, swq, bq, qqd, qqs,
      qwk, swk, bk, qkd, qks,
      qwv, swv, bv, vt2);

  attn_kernel<<<dim3(SEQ / 32, NHEAD, BATCH), 256, 0, stream>>>(
      qqd, qqs, qkd, qks, vt2, ctx, g_pla);

  quant_rows<<<R_TOT, 256, 0, stream>>>(ctx, HID, qc, scs);
  proj_out<<<dim3(R_TOT / 128, HID / 64), 256, 0, stream>>>(
      qc, scs, qwo, swo, bo, out);
}

// Round 12
// 153.670 us; speedup vs baseline: 1.8092x; 1.0588x over previous
//
#include <hip/hip_runtime.h>
#include <cmath>

#define R_TOT 4096   // B*S rows
#define HID   768
#define NHEAD 12
#define HDIM  64
#define SEQ   512
#define BATCH 8

typedef int   v4i  __attribute__((ext_vector_type(4)));
typedef float v4f  __attribute__((ext_vector_type(4)));
typedef _Float16 half8 __attribute__((ext_vector_type(8)));
typedef _Float16 half4v __attribute__((ext_vector_type(4)));

// ---------------- PLA coefficients (host, replicates np.polyfit in f64) ----
struct PlaConsts { float m[12]; float c[12]; float b[13]; };

static PlaConsts build_pla() {
  PlaConsts pc;
  const int NPTS = 1001;
  static double xs[NPTS], ys[NPTS];
  const double step = 10.0 / 1000.0;
  for (int j = 0; j < NPTS; ++j) xs[j] = (double)j * step + (-10.0);
  xs[NPTS - 1] = 0.0;
  for (int j = 0; j < NPTS; ++j) ys[j] = std::exp(xs[j]);
  double bnd[13];
  const double step2 = 10.0 / 12.0;
  for (int k = 0; k < 13; ++k) bnd[k] = (double)k * step2 + (-10.0);
  bnd[12] = 0.0;
  for (int i = 0; i < 12; ++i) {
    const double a = bnd[i], bb = bnd[i + 1];
    double sx = 0, sy = 0; int n = 0;
    for (int j = 0; j < NPTS; ++j)
      if (xs[j] >= a && xs[j] <= bb) { sx += xs[j]; sy += ys[j]; ++n; }
    const double xm = sx / n, ym = sy / n;
    double sxx = 0, sxy = 0;
    for (int j = 0; j < NPTS; ++j)
      if (xs[j] >= a && xs[j] <= bb) {
        const double dx = xs[j] - xm;
        sxx += dx * dx; sxy += dx * (ys[j] - ym);
      }
    const double m = sxy / sxx;
    pc.m[i] = (float)m;
    pc.c[i] = (float)(ym - m * xm);
  }
  for (int k = 0; k < 13; ++k) pc.b[k] = (float)bnd[k];
  return pc;
}
static const PlaConsts g_pla = build_pla();

// ---------------- per-row abs-max int8 quantization (768 cols) -------------
// Single global read pass: row cached in 3 registers (768 = 3*256).
__device__ __forceinline__ void quant_row_body(const float* __restrict__ x,
                                               signed char* __restrict__ qrow,
                                               float* __restrict__ srow) {
  const float v0 = x[threadIdx.x];
  const float v1 = x[threadIdx.x + 256];
  const float v2 = x[threadIdx.x + 512];
  float m = fmaxf(fmaxf(fabsf(v0), fabsf(v1)), fabsf(v2));
  #pragma unroll
  for (int off = 32; off; off >>= 1) m = fmaxf(m, __shfl_xor(m, off));
  __shared__ float red[4];
  const int lane = threadIdx.x & 63, wv = threadIdx.x >> 6;
  if (lane == 0) red[wv] = m;
  __syncthreads();
  if (threadIdx.x == 0) {
    float mm = fmaxf(fmaxf(red[0], red[1]), fmaxf(red[2], red[3]));
    float s = mm / 127.0f;
    if (s == 0.f) s = 1.f;
    red[0] = s;
    *srow = s;
  }
  __syncthreads();
  const float s = red[0];
  qrow[threadIdx.x] =
      (signed char)(int)fminf(fmaxf(rintf(v0 / s), -127.f), 127.f);
  qrow[threadIdx.x + 256] =
      (signed char)(int)fminf(fmaxf(rintf(v1 / s), -127.f), 127.f);
  qrow[threadIdx.x + 512] =
      (signed char)(int)fminf(fmaxf(rintf(v2 / s), -127.f), 127.f);
}

__global__ __launch_bounds__(256)
void quant_rows(const float* __restrict__ src,
                signed char* __restrict__ qout, float* __restrict__ sout) {
  const int row = blockIdx.x;
  quant_row_body(src + (size_t)row * HID, qout + (size_t)row * HID, sout + row);
}

// hidden states (4096 rows) + 4 weight matrices (4x768 rows) in ONE launch
__global__ __launch_bounds__(256)
void quant_all(const float* hs, const float* w0, const float* w1,
               const float* w2, const float* w3,
               signed char* qx, float* sx,
               signed char* q0, signed char* q1, signed char* q2, signed char* q3,
               float* s0, float* s1, float* s2, float* s3) {
  const int bid = blockIdx.x;
  const float* src; signed char* qo; float* so; int row;
  if (bid < R_TOT)            { src = hs; qo = qx; so = sx; row = bid; }
  else if (bid < R_TOT + 768) { src = w0; qo = q0; so = s0; row = bid - R_TOT; }
  else if (bid < R_TOT + 1536){ src = w1; qo = q1; so = s1; row = bid - R_TOT - 768; }
  else if (bid < R_TOT + 2304){ src = w2; qo = q2; so = s2; row = bid - R_TOT - 1536; }
  else                        { src = w3; qo = q3; so = s3; row = bid - R_TOT - 2304; }
  quant_row_body(src + (size_t)row * HID, qo + (size_t)row * HID, so + row);
}

// ---------------- int8 MFMA GEMM body: 128x64 tile, BK=128 -----------------
// mode 0: fp32 dense out; mode 1: per-head int8 (bhsd) + scales;
// mode 2: V path -> fp16 k-chunked transposed vt2[hb][k>>5][d][k&31]
__device__ __forceinline__
void proj_body(int mode,
               const signed char* __restrict__ qx, const float* __restrict__ sx,
               const signed char* __restrict__ qw, const float* __restrict__ sw,
               const float* __restrict__ bias,
               signed char* __restrict__ qo, float* __restrict__ so,
               _Float16* __restrict__ vt, float* __restrict__ fo,
               signed char* Al, signed char* Bl) {
  const int tid = threadIdx.x;
  const int w = tid >> 6, lane = tid & 63;
  const int n = lane & 15, quad = lane >> 4;
  const int row0 = blockIdx.x * 128, col0 = blockIdx.y * 64;
  const int ar = tid >> 1, ac = (tid & 1) * 64;   // A: 1 row, 64B contiguous
  const int br = tid >> 2, bc = (tid & 3) * 32;   // B: 1 row, 32B contiguous
  v4i acc[2][4];
  #pragma unroll
  for (int s = 0; s < 2; ++s)
    #pragma unroll
    for (int j = 0; j < 4; ++j) acc[s][j] = (v4i){0, 0, 0, 0};
  for (int k0 = 0; k0 < HID; k0 += 128) {
    const signed char* ap = qx + (size_t)(row0 + ar) * HID + k0 + ac;
    const int4 a0 = *(const int4*)(ap);
    const int4 a1 = *(const int4*)(ap + 16);
    const int4 a2 = *(const int4*)(ap + 32);
    const int4 a3 = *(const int4*)(ap + 48);
    const signed char* bp = qw + (size_t)(col0 + br) * HID + k0 + bc;
    const int4 b0 = *(const int4*)(bp);
    const int4 b1 = *(const int4*)(bp + 16);
    if (k0) __syncthreads();
    *(int4*)&Al[ar * 144 + ac]      = a0;
    *(int4*)&Al[ar * 144 + ac + 16] = a1;
    *(int4*)&Al[ar * 144 + ac + 32] = a2;
    *(int4*)&Al[ar * 144 + ac + 48] = a3;
    *(int4*)&Bl[br * 144 + bc]      = b0;
    *(int4*)&Bl[br * 144 + bc + 16] = b1;
    __syncthreads();
    #pragma unroll
    for (int ks = 0; ks < 128; ks += 64) {
      const v4i af0 = *(const v4i*)&Al[(w * 16 + n) * 144 + ks + quad * 16];
      const v4i af1 = *(const v4i*)&Al[(64 + w * 16 + n) * 144 + ks + quad * 16];
      #pragma unroll
      for (int j = 0; j < 4; ++j) {
        const v4i bf = *(const v4i*)&Bl[(j * 16 + n) * 144 + ks + quad * 16];
        acc[0][j] = __builtin_amdgcn_mfma_i32_16x16x64_i8(af0, bf, acc[0][j], 0, 0, 0);
        acc[1][j] = __builtin_amdgcn_mfma_i32_16x16x64_i8(af1, bf, acc[1][j], 0, 0, 0);
      }
    }
  }
  float swc4[4], bc4[4];
  #pragma unroll
  for (int j = 0; j < 4; ++j) {
    swc4[j] = sw[col0 + j * 16 + n];
    bc4[j] = bias[col0 + j * 16 + n];
  }
  #pragma unroll
  for (int s = 0; s < 2; ++s) {
    const int mrow = s * 64 + w * 16 + quad * 4;
    float sxr[4];
    #pragma unroll
    for (int r = 0; r < 4; ++r) sxr[r] = sx[row0 + mrow + r];
    float vals[4][4];  // [j][r]
    #pragma unroll
    for (int j = 0; j < 4; ++j)
      #pragma unroll
      for (int r = 0; r < 4; ++r)
        vals[j][r] = (float)acc[s][j][r] * (sxr[r] * swc4[j]) + bc4[j];
    if (mode == 1) {
      const int h = blockIdx.y;
      #pragma unroll
      for (int r = 0; r < 4; ++r) {
        float m = 0.f;
        #pragma unroll
        for (int j = 0; j < 4; ++j) m = fmaxf(m, fabsf(vals[j][r]));
        #pragma unroll
        for (int off = 1; off < 16; off <<= 1) m = fmaxf(m, __shfl_xor(m, off));
        float sq = m / 127.0f;
        if (sq == 0.f) sq = 1.f;
        const int grow = row0 + mrow + r;
        const int bidx = grow >> 9, sidx = grow & 511;
        const size_t rowidx = ((size_t)bidx * NHEAD + h) * SEQ + sidx;
        #pragma unroll
        for (int j = 0; j < 4; ++j) {
          float q = fminf(fmaxf(rintf(vals[j][r] / sq), -127.f), 127.f);
          qo[rowidx * HDIM + j * 16 + n] = (signed char)(int)q;
        }
        if (n == 0) so[rowidx] = sq;
      }
    } else if (mode == 2) {
      const int h = blockIdx.y;
      float srow[4];
      #pragma unroll
      for (int r = 0; r < 4; ++r) {
        float m = 0.f;
        #pragma unroll
        for (int j = 0; j < 4; ++j) m = fmaxf(m, fabsf(vals[j][r]));
        #pragma unroll
        for (int off = 1; off < 16; off <<= 1) m = fmaxf(m, __shfl_xor(m, off));
        float sq = m / 127.0f;
        if (sq == 0.f) sq = 1.f;
        srow[r] = sq;
      }
      const int grow0 = row0 + mrow;         // 4 consecutive k, same batch
      const int bidx = grow0 >> 9, sidx = grow0 & 511;
      const int kb = sidx >> 5, ko = sidx & 31;
      const size_t hbv = (size_t)bidx * NHEAD + h;
      #pragma unroll
      for (int j = 0; j < 4; ++j) {
        half4v hv;
        #pragma unroll
        for (int r = 0; r < 4; ++r) {
          float q = fminf(fmaxf(rintf(vals[j][r] / srow[r]), -127.f), 127.f);
          hv[r] = (_Float16)(q * srow[r]);
        }
        *(half4v*)(vt + ((hbv * 16 + kb) * 64 + j * 16 + n) * 32 + ko) = hv;
      }
    } else {
      #pragma unroll
      for (int r = 0; r < 4; ++r) {
        const size_t base = (size_t)(row0 + mrow + r) * HID + col0;
        #pragma unroll
        for (int j = 0; j < 4; ++j)
          fo[base + j * 16 + n] = vals[j][r];
      }
    }
  }
}

// fused Q/K/V projections: blockIdx.z selects weight/output
__global__ __launch_bounds__(256)
void proj_qkv(const signed char* __restrict__ qx, const float* __restrict__ sx,
              const signed char* qwq, const float* swq, const float* bq,
              signed char* qqd, float* qqs,
              const signed char* qwk, const float* swk, const float* bk,
              signed char* qkd, float* qks,
              const signed char* qwv, const float* swv, const float* bv,
              _Float16* vt2) {
  __shared__ __align__(16) signed char Al[128 * 144];
  __shared__ __align__(16) signed char Bl[64 * 144];
  if (blockIdx.z == 0)
    proj_body(1, qx, sx, qwq, swq, bq, qqd, qqs, nullptr, nullptr, Al, Bl);
  else if (blockIdx.z == 1)
    proj_body(1, qx, sx, qwk, swk, bk, qkd, qks, nullptr, nullptr, Al, Bl);
  else
    proj_body(2, qx, sx, qwv, swv, bv, nullptr, nullptr, vt2, nullptr, Al, Bl);
}

__global__ __launch_bounds__(256)
void proj_out(const signed char* __restrict__ qx, const float* __restrict__ sx,
              const signed char* qw, const float* sw, const float* bias,
              float* fo) {
  __shared__ __align__(16) signed char Al[128 * 144];
  __shared__ __align__(16) signed char Bl[64 * 144];
  proj_body(0, qx, sx, qw, sw, bias, nullptr, nullptr, nullptr, fo, Al, Bl);
}

// ---------------- attention helpers ---------------------------------------
// PLA exp over one 16-row tile held in registers. pt4[g] = (b_g, b_{g+1},
// m_g, c_g): one ds_read_b128 per element; boundary fixup re-reads rarely.
__device__ __forceinline__
void softmax_exp_tile(float (&s)[8][4], float mx26, const float4* __restrict__ pt4,
                      float& sum_out, float& amax_out) {
  float sum = 0.f, amax = 0.f;
  #pragma unroll
  for (int t = 0; t < 8; ++t) {
    #pragma unroll
    for (int r = 0; r < 4; ++r) {
      float sh = s[t][r] - mx26;              // == (s-mx)*2^26 exactly
      sh = fmaxf(sh, -671088640.0f);          // clamp at -10*2^26
      const float tq = rintf(sh);
      const float xc = tq * 1.4901161193847656e-08f;  // *2^-26 (exact)
      int g = (int)((xc + 10.0f) * 1.2f);     // >=0 since xc>=-10
      g = g > 11 ? 11 : g;
      float4 E = pt4[g];
      int gn = g + ((xc >= E.y) ? 1 : 0) - ((xc < E.x) ? 1 : 0);
      gn = gn < 0 ? 0 : (gn > 11 ? 11 : gn);
      if (gn != g) E = pt4[gn];               // rare boundary fixup
      const float e = __fadd_rn(__fmul_rn(E.z, xc), E.w);
      s[t][r] = e;
      sum += e;
      amax = fmaxf(amax, fabsf(e));
    }
  }
  sum += __shfl_xor(sum, 16);
  sum += __shfl_xor(sum, 32);
  amax = fmaxf(amax, __shfl_xor(amax, 16));
  amax = fmaxf(amax, __shfl_xor(amax, 32));
  sum_out = sum; amax_out = amax;
}

// quantize probs: qf = rint(e * (127/am)) — rden cancels algebraically.
__device__ __forceinline__
void quant_pack_tile(const float (&s)[8][4], float t127,
                     _Float16* __restrict__ phtrow, int w, int quad) {
  #pragma unroll
  for (int t = 0; t < 8; ++t) {
    half4v hq;
    #pragma unroll
    for (int r = 0; r < 4; ++r) {
      const float qf = fminf(fmaxf(rintf(s[t][r] * t127), -127.f), 127.f);
      hq[r] = (_Float16)qf;
    }
    *(half4v*)&phtrow[(t * 4 + w) * 16 + quad * 4] = hq;
  }
}

__device__ __forceinline__
v4f pv_tile(const _Float16* __restrict__ vbase, const _Float16* __restrict__ prow) {
  v4f acc = {0.f, 0.f, 0.f, 0.f};
  #pragma unroll
  for (int kt = 0; kt < 16; ++kt) {
    const half8 bf = *(const half8*)(vbase + kt * 2048);
    acc = __builtin_amdgcn_mfma_f32_16x16x32_f16(*(const half8*)(prow + kt * 32), bf, acc, 0, 0, 0);
  }
  return acc;
}

// ---------------- fused attention: dual-tile, overlapped phases ------------
// P1(both) | 2a(t0) | 2b(t0)+2a(t1) | PV(t0)+2b(t1) | PV(t1)  — 4 barriers.
// Double PhT (LDS ~35 KB, 4 blocks/CU): LDS caps occupancy regardless
// (R11: 17.9 KB was neutral), so spend it on cross-tile pipelining; VGPR
// inflation up to 128 is free at this LDS size.
#define PSTR 520  // PhT row stride in halves (16B-aligned rows)
__global__ __launch_bounds__(256)
void attn_kernel(const signed char* __restrict__ qq, const float* __restrict__ qss,
                 const signed char* __restrict__ qk, const float* __restrict__ kss,
                 const _Float16* __restrict__ vt2,
                 float* __restrict__ ctx, const PlaConsts pc) {
  __shared__ __align__(16) _Float16 PhT[2][16 * PSTR];
  __shared__ __align__(16) float red_max[2][16][4];
  __shared__ __align__(16) float red_sum[2][16][4];
  __shared__ __align__(16) float red_amax[2][16][4];
  __shared__ float psa[2][16];
  __shared__ __align__(16) float4 pt4[12];

  const int tid = threadIdx.x;
  const int q0 = blockIdx.x * 32;
  const int hh = blockIdx.y, bz = blockIdx.z;
  const size_t hb = (size_t)bz * NHEAD + hh;
  const signed char* qqh = qq + (hb * SEQ + q0) * HDIM;
  const signed char* qkh = qk + hb * SEQ * HDIM;
  const float* ksp = kss + hb * SEQ;

  if (tid < 12)
    pt4[tid] = make_float4(pc.b[tid], pc.b[tid + 1], pc.m[tid], pc.c[tid]);

  const int w = tid >> 6, lane = tid & 63;
  const int n = lane & 15, quad = lane >> 4;

  // ---- Phase 1: S^T via i8 MFMA (A=K rows, B=Q rows), two q-tiles ----
  float s26[2][8][4];
  {
    const v4i qf0 = *(const v4i*)(qqh + (size_t)n * HDIM + quad * 16);
    const v4i qf1 = *(const v4i*)(qqh + (size_t)(16 + n) * HDIM + quad * 16);
    const float qs0 = (qss[hb * SEQ + q0 + n] * 0.125f) * 67108864.0f;
    const float qs1 = (qss[hb * SEQ + q0 + 16 + n] * 0.125f) * 67108864.0f;
    float vmax0 = -3.0e38f, vmax1 = -3.0e38f;
    #pragma unroll
    for (int t = 0; t < 8; ++t) {
      const int kc0 = (t * 4 + w) * 16;
      const v4i kfrag = *(const v4i*)(qkh + (size_t)(kc0 + n) * HDIM + quad * 16);
      const float4 ks4 = *(const float4*)(ksp + kc0 + quad * 4);
      v4i zero = {};
      const v4i a0 = __builtin_amdgcn_mfma_i32_16x16x64_i8(kfrag, qf0, zero, 0, 0, 0);
      const v4i a1 = __builtin_amdgcn_mfma_i32_16x16x64_i8(kfrag, qf1, zero, 0, 0, 0);
      const float ks[4] = {ks4.x, ks4.y, ks4.z, ks4.w};
      #pragma unroll
      for (int r = 0; r < 4; ++r) {
        const float v0 = (float)a0[r] * (qs0 * ks[r]);
        const float v1 = (float)a1[r] * (qs1 * ks[r]);
        s26[0][t][r] = v0; vmax0 = fmaxf(vmax0, v0);
        s26[1][t][r] = v1; vmax1 = fmaxf(vmax1, v1);
      }
    }
    vmax0 = fmaxf(vmax0, __shfl_xor(vmax0, 16));
    vmax0 = fmaxf(vmax0, __shfl_xor(vmax0, 32));
    vmax1 = fmaxf(vmax1, __shfl_xor(vmax1, 16));
    vmax1 = fmaxf(vmax1, __shfl_xor(vmax1, 32));
    if (quad == 0) { red_max[0][n][w] = vmax0; red_max[1][n][w] = vmax1; }
  }
  __syncthreads();  // bar1

  // ---- Phase B: 2a(t0) ----
  {
    const float4 rm = *(const float4*)&red_max[0][n][0];
    const float mx26 = fmaxf(fmaxf(rm.x, rm.y), fmaxf(rm.z, rm.w));
    float sum, amax;
    softmax_exp_tile(s26[0], mx26, pt4, sum, amax);
    if (quad == 0) { red_sum[0][n][w] = sum; red_amax[0][n][w] = amax; }
  }
  __syncthreads();  // bar2

  // ---- Phase C: 2b(t0) -> PhT[0]  +  2a(t1) ----
  {
    const float4 rs = *(const float4*)&red_sum[0][n][0];
    const float4 ra = *(const float4*)&red_amax[0][n][0];
    float denom = (rs.x + rs.y) + (rs.z + rs.w);
    denom = __fadd_rn(denom, 1e-9f);
    const float rden = 1.0f / denom;
    const float am = fmaxf(fmaxf(ra.x, ra.y), fmaxf(ra.z, ra.w));
    float ps = (am * rden) / 127.0f;
    if (ps == 0.f) ps = 1.f;
    if (w == 0 && quad == 0) psa[0][n] = ps;
    const float t127 = 127.0f / am;
    quant_pack_tile(s26[0], t127, &PhT[0][n * PSTR], w, quad);

    const float4 rm = *(const float4*)&red_max[1][n][0];
    const float mx26 = fmaxf(fmaxf(rm.x, rm.y), fmaxf(rm.z, rm.w));
    float sum, amax;
    softmax_exp_tile(s26[1], mx26, pt4, sum, amax);
    if (quad == 0) { red_sum[1][n][w] = sum; red_amax[1][n][w] = amax; }
  }
  __syncthreads();  // bar3

  const _Float16* vbase = vt2 + ((size_t)hb * 16 * 64 + (w * 16 + n)) * 32 + quad * 8;

  // ---- Phase D: PV(t0)  +  2b(t1) -> PhT[1] ----
  {
    const v4f acc0 = pv_tile(vbase, &PhT[0][n * PSTR + quad * 8]);

    const float4 rs = *(const float4*)&red_sum[1][n][0];
    const float4 ra = *(const float4*)&red_amax[1][n][0];
    float denom = (rs.x + rs.y) + (rs.z + rs.w);
    denom = __fadd_rn(denom, 1e-9f);
    const float rden = 1.0f / denom;
    const float am = fmaxf(fmaxf(ra.x, ra.y), fmaxf(ra.z, ra.w));
    float ps = (am * rden) / 127.0f;
    if (ps == 0.f) ps = 1.f;
    if (w == 0 && quad == 0) psa[1][n] = ps;
    const float t127 = 127.0f / am;
    quant_pack_tile(s26[1], t127, &PhT[1][n * PSTR], w, quad);

    #pragma unroll
    for (int r = 0; r < 4; ++r) {
      const int row = quad * 4 + r;
      ctx[((size_t)bz * SEQ + q0 + row) * HID + (size_t)hh * HDIM + w * 16 + n] =
          acc0[r] * psa[0][row];
    }
  }
  __syncthreads();  // bar4

  // ---- Phase E: PV(t1) ----
  {
    const v4f acc1 = pv_tile(vbase, &PhT[1][n * PSTR + quad * 8]);
    #pragma unroll
    for (int r = 0; r < 4; ++r) {
      const int row = quad * 4 + r;
      ctx[((size_t)bz * SEQ + q0 + 16 + row) * HID + (size_t)hh * HDIM + w * 16 + n] =
          acc1[r] * psa[1][row];
    }
  }
}

// --------------------------------------------------------------------------
extern "C" void kernel_launch(void* const* d_in, const int* in_sizes, int n_in,
                              void* d_out, int out_size, void* d_ws, size_t ws_size,
                              hipStream_t stream) {
  (void)in_sizes; (void)n_in; (void)out_size; (void)ws_size;
  const float* hs = (const float*)d_in[0];
  const float* Wq = (const float*)d_in[1];
  const float* bq = (const float*)d_in[2];
  const float* Wk = (const float*)d_in[3];
  const float* bk = (const float*)d_in[4];
  const float* Wv = (const float*)d_in[5];
  const float* bv = (const float*)d_in[6];
  const float* Wo = (const float*)d_in[7];
  const float* bo = (const float*)d_in[8];
  float* out = (float*)d_out;

  char* ws = (char*)d_ws;
  size_t off = 0;
  auto alloc = [&](size_t bytes) -> char* {
    char* p = ws + off;
    off += (bytes + 255) & ~(size_t)255;
    return p;
  };
  signed char* qx  = (signed char*)alloc((size_t)R_TOT * HID);
  float*       sx  = (float*)alloc((size_t)R_TOT * 4);
  signed char* qwq = (signed char*)alloc((size_t)HID * HID);
  signed char* qwk = (signed char*)alloc((size_t)HID * HID);
  signed char* qwv = (signed char*)alloc((size_t)HID * HID);
  signed char* qwo = (signed char*)alloc((size_t)HID * HID);
  float*       swq = (float*)alloc((size_t)HID * 4);
  float*       swk = (float*)alloc((size_t)HID * 4);
  float*       swv = (float*)alloc((size_t)HID * 4);
  float*       swo = (float*)alloc((size_t)HID * 4);
  signed char* qqd = (signed char*)alloc((size_t)R_TOT * HID);
  float*       qqs = (float*)alloc((size_t)BATCH * NHEAD * SEQ * 4);
  signed char* qkd = (signed char*)alloc((size_t)R_TOT * HID);
  float*       qks = (float*)alloc((size_t)BATCH * NHEAD * SEQ * 4);
  float*       ctx = (float*)alloc((size_t)R_TOT * HID * 4);
  _Float16*    vt2 = (_Float16*)alloc((size_t)BATCH * NHEAD * HDIM * SEQ * 2);
  // alias: qx/sx are dead after the QKV projections
  signed char* qc  = qx;
  float*       scs = sx;

  quant_all<<<R_TOT + 4 * HID, 256, 0, stream>>>(
      hs, Wq, Wk, Wv, Wo, qx, sx,
      qwq, qwk, qwv, qwo, swq, swk, swv, swo);

  proj_qkv<<<dim3(R_TOT / 128, HID / 64, 3), 256, 0, stream>>>(
      qx, sx, qwq, swq, bq, qqd, qqs,
      qwk, swk, bk, qkd, qks,
      qwv, swv, bv, vt2);

  attn_kernel<<<dim3(SEQ / 32, NHEAD, BATCH), 256, 0, stream>>>(
      qqd, qqs, qkd, qks, vt2, ctx, g_pla);

  quant_rows<<<R_TOT, 256, 0, stream>>>(ctx, qc, scs);
  proj_out<<<dim3(R_TOT / 128, HID / 64), 256, 0, stream>>>(
      qc, scs, qwo, swo, bo, out);
}

// Round 13
// 149.754 us; speedup vs baseline: 1.8565x; 1.0261x over previous
//
#include <hip/hip_runtime.h>
#include <cmath>

#define R_TOT 4096   // B*S rows
#define HID   768
#define NHEAD 12
#define HDIM  64
#define SEQ   512
#define BATCH 8

typedef int   v4i  __attribute__((ext_vector_type(4)));
typedef float v4f  __attribute__((ext_vector_type(4)));
typedef _Float16 half8 __attribute__((ext_vector_type(8)));
typedef _Float16 half4v __attribute__((ext_vector_type(4)));

// Direct global->LDS DMA, 16B per lane. HW semantics (m104/m108): dest =
// readfirstlane(ldsptr) + lane*16 — pass the wave-uniform chunk base.
__device__ __forceinline__ void gl_lds16(const signed char* g, signed char* l) {
  __builtin_amdgcn_global_load_lds(
      (const __attribute__((address_space(1))) void*)g,
      (__attribute__((address_space(3))) void*)l, 16, 0, 0);
}

// ---------------- PLA coefficients (host, replicates np.polyfit in f64) ----
struct PlaConsts { float m[12]; float c[12]; float b[13]; };

static PlaConsts build_pla() {
  PlaConsts pc;
  const int NPTS = 1001;
  static double xs[NPTS], ys[NPTS];
  const double step = 10.0 / 1000.0;
  for (int j = 0; j < NPTS; ++j) xs[j] = (double)j * step + (-10.0);
  xs[NPTS - 1] = 0.0;
  for (int j = 0; j < NPTS; ++j) ys[j] = std::exp(xs[j]);
  double bnd[13];
  const double step2 = 10.0 / 12.0;
  for (int k = 0; k < 13; ++k) bnd[k] = (double)k * step2 + (-10.0);
  bnd[12] = 0.0;
  for (int i = 0; i < 12; ++i) {
    const double a = bnd[i], bb = bnd[i + 1];
    double sx = 0, sy = 0; int n = 0;
    for (int j = 0; j < NPTS; ++j)
      if (xs[j] >= a && xs[j] <= bb) { sx += xs[j]; sy += ys[j]; ++n; }
    const double xm = sx / n, ym = sy / n;
    double sxx = 0, sxy = 0;
    for (int j = 0; j < NPTS; ++j)
      if (xs[j] >= a && xs[j] <= bb) {
        const double dx = xs[j] - xm;
        sxx += dx * dx; sxy += dx * (ys[j] - ym);
      }
    const double m = sxy / sxx;
    pc.m[i] = (float)m;
    pc.c[i] = (float)(ym - m * xm);
  }
  for (int k = 0; k < 13; ++k) pc.b[k] = (float)bnd[k];
  return pc;
}
static const PlaConsts g_pla = build_pla();

// ---------------- per-row abs-max int8 quantization (768 cols) -------------
__device__ __forceinline__ void quant_row_body(const float* __restrict__ x,
                                               signed char* __restrict__ qrow,
                                               float* __restrict__ srow) {
  const float v0 = x[threadIdx.x];
  const float v1 = x[threadIdx.x + 256];
  const float v2 = x[threadIdx.x + 512];
  float m = fmaxf(fmaxf(fabsf(v0), fabsf(v1)), fabsf(v2));
  #pragma unroll
  for (int off = 32; off; off >>= 1) m = fmaxf(m, __shfl_xor(m, off));
  __shared__ float red[4];
  const int lane = threadIdx.x & 63, wv = threadIdx.x >> 6;
  if (lane == 0) red[wv] = m;
  __syncthreads();
  if (threadIdx.x == 0) {
    float mm = fmaxf(fmaxf(red[0], red[1]), fmaxf(red[2], red[3]));
    float s = mm / 127.0f;
    if (s == 0.f) s = 1.f;
    red[0] = s;
    *srow = s;
  }
  __syncthreads();
  const float s = red[0];
  qrow[threadIdx.x] =
      (signed char)(int)fminf(fmaxf(rintf(v0 / s), -127.f), 127.f);
  qrow[threadIdx.x + 256] =
      (signed char)(int)fminf(fmaxf(rintf(v1 / s), -127.f), 127.f);
  qrow[threadIdx.x + 512] =
      (signed char)(int)fminf(fmaxf(rintf(v2 / s), -127.f), 127.f);
}

__global__ __launch_bounds__(256)
void quant_rows(const float* __restrict__ src,
                signed char* __restrict__ qout, float* __restrict__ sout) {
  const int row = blockIdx.x;
  quant_row_body(src + (size_t)row * HID, qout + (size_t)row * HID, sout + row);
}

__global__ __launch_bounds__(256)
void quant_all(const float* hs, const float* w0, const float* w1,
               const float* w2, const float* w3,
               signed char* qx, float* sx,
               signed char* q0, signed char* q1, signed char* q2, signed char* q3,
               float* s0, float* s1, float* s2, float* s3) {
  const int bid = blockIdx.x;
  const float* src; signed char* qo; float* so; int row;
  if (bid < R_TOT)            { src = hs; qo = qx; so = sx; row = bid; }
  else if (bid < R_TOT + 768) { src = w0; qo = q0; so = s0; row = bid - R_TOT; }
  else if (bid < R_TOT + 1536){ src = w1; qo = q1; so = s1; row = bid - R_TOT - 768; }
  else if (bid < R_TOT + 2304){ src = w2; qo = q2; so = s2; row = bid - R_TOT - 1536; }
  else                        { src = w3; qo = q3; so = s3; row = bid - R_TOT - 2304; }
  quant_row_body(src + (size_t)row * HID, qo + (size_t)row * HID, so + row);
}

// ---------------- int8 MFMA GEMM body: 128x64 tile, BK=128 -----------------
// Staging via global_load_lds width=16 (m97 ladder step): per k-iter each
// wave issues 4 A-chunk + 2 B-chunk DMAs (chunk = 8 rows x 128B = 1KB,
// lane i -> base + i*16). LDS stride 128 with XOR swizzle: slot s of row r
// holds global col16 s^(r&7); global fetch col is permuted to match
// (cg = lc^lr), so 128B segments stay fully coalesced. MFMA reads apply the
// inverse swizzle; ds_read_b128 stays at its 8-way bank floor. Same values
// into the same MFMAs -> bit-exact vs R12.
// mode 0: fp32 dense out; mode 1: per-head int8 (bhsd) + scales;
// mode 2: V path -> fp16 k-chunked transposed vt2[hb][k>>5][d][k&31]
__device__ __forceinline__
void proj_body(int mode,
               const signed char* __restrict__ qx, const float* __restrict__ sx,
               const signed char* __restrict__ qw, const float* __restrict__ sw,
               const float* __restrict__ bias,
               signed char* __restrict__ qo, float* __restrict__ so,
               _Float16* __restrict__ vt, float* __restrict__ fo,
               signed char* Al, signed char* Bl) {
  const int tid = threadIdx.x;
  const int w = tid >> 6, lane = tid & 63;
  const int n = lane & 15, quad = lane >> 4;
  const int row0 = blockIdx.x * 128, col0 = blockIdx.y * 64;
  const int lr = lane >> 3;          // row within 8-row chunk
  const int lc = lane & 7;           // col16 slot
  const int cg = lc ^ lr;            // swizzled global col16 to fetch
  v4i acc[2][4];
  #pragma unroll
  for (int s = 0; s < 2; ++s)
    #pragma unroll
    for (int j = 0; j < 4; ++j) acc[s][j] = (v4i){0, 0, 0, 0};
  for (int k0 = 0; k0 < HID; k0 += 128) {
    if (k0) __syncthreads();
    #pragma unroll
    for (int m = 0; m < 4; ++m) {
      const int ci = w * 4 + m;                     // A chunk 0..15
      gl_lds16(qx + (size_t)(row0 + ci * 8 + lr) * HID + k0 + cg * 16,
               Al + ci * 1024);
    }
    #pragma unroll
    for (int m = 0; m < 2; ++m) {
      const int ci = w * 2 + m;                     // B chunk 0..7
      gl_lds16(qw + (size_t)(col0 + ci * 8 + lr) * HID + k0 + cg * 16,
               Bl + ci * 1024);
    }
    __syncthreads();
    #pragma unroll
    for (int ks4 = 0; ks4 < 8; ks4 += 4) {
      const int sw16 = ((quad + ks4) ^ (n & 7)) * 16;   // inverse swizzle
      const v4i af0 = *(const v4i*)&Al[(w * 16 + n) * 128 + sw16];
      const v4i af1 = *(const v4i*)&Al[(64 + w * 16 + n) * 128 + sw16];
      #pragma unroll
      for (int j = 0; j < 4; ++j) {
        const v4i bf = *(const v4i*)&Bl[(j * 16 + n) * 128 + sw16];
        acc[0][j] = __builtin_amdgcn_mfma_i32_16x16x64_i8(af0, bf, acc[0][j], 0, 0, 0);
        acc[1][j] = __builtin_amdgcn_mfma_i32_16x16x64_i8(af1, bf, acc[1][j], 0, 0, 0);
      }
    }
  }
  float swc4[4], bc4[4];
  #pragma unroll
  for (int j = 0; j < 4; ++j) {
    swc4[j] = sw[col0 + j * 16 + n];
    bc4[j] = bias[col0 + j * 16 + n];
  }
  #pragma unroll
  for (int s = 0; s < 2; ++s) {
    const int mrow = s * 64 + w * 16 + quad * 4;
    float sxr[4];
    #pragma unroll
    for (int r = 0; r < 4; ++r) sxr[r] = sx[row0 + mrow + r];
    float vals[4][4];  // [j][r]
    #pragma unroll
    for (int j = 0; j < 4; ++j)
      #pragma unroll
      for (int r = 0; r < 4; ++r)
        vals[j][r] = (float)acc[s][j][r] * (sxr[r] * swc4[j]) + bc4[j];
    if (mode == 1) {
      const int h = blockIdx.y;
      #pragma unroll
      for (int r = 0; r < 4; ++r) {
        float m = 0.f;
        #pragma unroll
        for (int j = 0; j < 4; ++j) m = fmaxf(m, fabsf(vals[j][r]));
        #pragma unroll
        for (int off = 1; off < 16; off <<= 1) m = fmaxf(m, __shfl_xor(m, off));
        float sq = m / 127.0f;
        if (sq == 0.f) sq = 1.f;
        const int grow = row0 + mrow + r;
        const int bidx = grow >> 9, sidx = grow & 511;
        const size_t rowidx = ((size_t)bidx * NHEAD + h) * SEQ + sidx;
        #pragma unroll
        for (int j = 0; j < 4; ++j) {
          float q = fminf(fmaxf(rintf(vals[j][r] / sq), -127.f), 127.f);
          qo[rowidx * HDIM + j * 16 + n] = (signed char)(int)q;
        }
        if (n == 0) so[rowidx] = sq;
      }
    } else if (mode == 2) {
      const int h = blockIdx.y;
      float srow[4];
      #pragma unroll
      for (int r = 0; r < 4; ++r) {
        float m = 0.f;
        #pragma unroll
        for (int j = 0; j < 4; ++j) m = fmaxf(m, fabsf(vals[j][r]));
        #pragma unroll
        for (int off = 1; off < 16; off <<= 1) m = fmaxf(m, __shfl_xor(m, off));
        float sq = m / 127.0f;
        if (sq == 0.f) sq = 1.f;
        srow[r] = sq;
      }
      const int grow0 = row0 + mrow;         // 4 consecutive k, same batch
      const int bidx = grow0 >> 9, sidx = grow0 & 511;
      const int kb = sidx >> 5, ko = sidx & 31;
      const size_t hbv = (size_t)bidx * NHEAD + h;
      #pragma unroll
      for (int j = 0; j < 4; ++j) {
        half4v hv;
        #pragma unroll
        for (int r = 0; r < 4; ++r) {
          float q = fminf(fmaxf(rintf(vals[j][r] / srow[r]), -127.f), 127.f);
          hv[r] = (_Float16)(q * srow[r]);
        }
        *(half4v*)(vt + ((hbv * 16 + kb) * 64 + j * 16 + n) * 32 + ko) = hv;
      }
    } else {
      #pragma unroll
      for (int r = 0; r < 4; ++r) {
        const size_t base = (size_t)(row0 + mrow + r) * HID + col0;
        #pragma unroll
        for (int j = 0; j < 4; ++j)
          fo[base + j * 16 + n] = vals[j][r];
      }
    }
  }
}

// fused Q/K/V projections: blockIdx.z selects weight/output
__global__ __launch_bounds__(256)
void proj_qkv(const signed char* __restrict__ qx, const float* __restrict__ sx,
              const signed char* qwq, const float* swq, const float* bq,
              signed char* qqd, float* qqs,
              const signed char* qwk, const float* swk, const float* bk,
              signed char* qkd, float* qks,
              const signed char* qwv, const float* swv, const float* bv,
              _Float16* vt2) {
  __shared__ __align__(16) signed char Al[128 * 128];
  __shared__ __align__(16) signed char Bl[64 * 128];
  if (blockIdx.z == 0)
    proj_body(1, qx, sx, qwq, swq, bq, qqd, qqs, nullptr, nullptr, Al, Bl);
  else if (blockIdx.z == 1)
    proj_body(1, qx, sx, qwk, swk, bk, qkd, qks, nullptr, nullptr, Al, Bl);
  else
    proj_body(2, qx, sx, qwv, swv, bv, nullptr, nullptr, vt2, nullptr, Al, Bl);
}

__global__ __launch_bounds__(256)
void proj_out(const signed char* __restrict__ qx, const float* __restrict__ sx,
              const signed char* qw, const float* sw, const float* bias,
              float* fo) {
  __shared__ __align__(16) signed char Al[128 * 128];
  __shared__ __align__(16) signed char Bl[64 * 128];
  proj_body(0, qx, sx, qw, sw, bias, nullptr, nullptr, nullptr, fo, Al, Bl);
}

// ---------------- attention helpers ---------------------------------------
__device__ __forceinline__
void softmax_exp_tile(float (&s)[8][4], float mx26, const float4* __restrict__ pt4,
                      float& sum_out, float& amax_out) {
  float sum = 0.f, amax = 0.f;
  #pragma unroll
  for (int t = 0; t < 8; ++t) {
    #pragma unroll
    for (int r = 0; r < 4; ++r) {
      float sh = s[t][r] - mx26;              // == (s-mx)*2^26 exactly
      sh = fmaxf(sh, -671088640.0f);          // clamp at -10*2^26
      const float tq = rintf(sh);
      const float xc = tq * 1.4901161193847656e-08f;  // *2^-26 (exact)
      int g = (int)((xc + 10.0f) * 1.2f);     // >=0 since xc>=-10
      g = g > 11 ? 11 : g;
      float4 E = pt4[g];
      int gn = g + ((xc >= E.y) ? 1 : 0) - ((xc < E.x) ? 1 : 0);
      gn = gn < 0 ? 0 : (gn > 11 ? 11 : gn);
      if (gn != g) E = pt4[gn];               // rare boundary fixup
      const float e = __fadd_rn(__fmul_rn(E.z, xc), E.w);
      s[t][r] = e;
      sum += e;
      amax = fmaxf(amax, fabsf(e));
    }
  }
  sum += __shfl_xor(sum, 16);
  sum += __shfl_xor(sum, 32);
  amax = fmaxf(amax, __shfl_xor(amax, 16));
  amax = fmaxf(amax, __shfl_xor(amax, 32));
  sum_out = sum; amax_out = amax;
}

__device__ __forceinline__
void quant_pack_tile(const float (&s)[8][4], float t127,
                     _Float16* __restrict__ phtrow, int w, int quad) {
  #pragma unroll
  for (int t = 0; t < 8; ++t) {
    half4v hq;
    #pragma unroll
    for (int r = 0; r < 4; ++r) {
      const float qf = fminf(fmaxf(rintf(s[t][r] * t127), -127.f), 127.f);
      hq[r] = (_Float16)qf;
    }
    *(half4v*)&phtrow[(t * 4 + w) * 16 + quad * 4] = hq;
  }
}

__device__ __forceinline__
v4f pv_tile(const _Float16* __restrict__ vbase, const _Float16* __restrict__ prow) {
  v4f acc = {0.f, 0.f, 0.f, 0.f};
  #pragma unroll
  for (int kt = 0; kt < 16; ++kt) {
    const half8 bf = *(const half8*)(vbase + kt * 2048);
    acc = __builtin_amdgcn_mfma_f32_16x16x32_f16(*(const half8*)(prow + kt * 32), bf, acc, 0, 0, 0);
  }
  return acc;
}

// ---------------- fused attention: dual-tile, overlapped phases ------------
// P1(both) | 2a(t0) | 2b(t0)+2a(t1) | PV(t0)+2b(t1) | PV(t1)  — 4 barriers.
#define PSTR 520  // PhT row stride in halves (16B-aligned rows)
__global__ __launch_bounds__(256)
void attn_kernel(const signed char* __restrict__ qq, const float* __restrict__ qss,
                 const signed char* __restrict__ qk, const float* __restrict__ kss,
                 const _Float16* __restrict__ vt2,
                 float* __restrict__ ctx, const PlaConsts pc) {
  __shared__ __align__(16) _Float16 PhT[2][16 * PSTR];
  __shared__ __align__(16) float red_max[2][16][4];
  __shared__ __align__(16) float red_sum[2][16][4];
  __shared__ __align__(16) float red_amax[2][16][4];
  __shared__ float psa[2][16];
  __shared__ __align__(16) float4 pt4[12];

  const int tid = threadIdx.x;
  const int q0 = blockIdx.x * 32;
  const int hh = blockIdx.y, bz = blockIdx.z;
  const size_t hb = (size_t)bz * NHEAD + hh;
  const signed char* qqh = qq + (hb * SEQ + q0) * HDIM;
  const signed char* qkh = qk + hb * SEQ * HDIM;
  const float* ksp = kss + hb * SEQ;

  if (tid < 12)
    pt4[tid] = make_float4(pc.b[tid], pc.b[tid + 1], pc.m[tid], pc.c[tid]);

  const int w = tid >> 6, lane = tid & 63;
  const int n = lane & 15, quad = lane >> 4;

  // ---- Phase 1: S^T via i8 MFMA (A=K rows, B=Q rows), two q-tiles ----
  float s26[2][8][4];
  {
    const v4i qf0 = *(const v4i*)(qqh + (size_t)n * HDIM + quad * 16);
    const v4i qf1 = *(const v4i*)(qqh + (size_t)(16 + n) * HDIM + quad * 16);
    const float qs0 = (qss[hb * SEQ + q0 + n] * 0.125f) * 67108864.0f;
    const float qs1 = (qss[hb * SEQ + q0 + 16 + n] * 0.125f) * 67108864.0f;
    float vmax0 = -3.0e38f, vmax1 = -3.0e38f;
    #pragma unroll
    for (int t = 0; t < 8; ++t) {
      const int kc0 = (t * 4 + w) * 16;
      const v4i kfrag = *(const v4i*)(qkh + (size_t)(kc0 + n) * HDIM + quad * 16);
      const float4 ks4 = *(const float4*)(ksp + kc0 + quad * 4);
      v4i zero = {};
      const v4i a0 = __builtin_amdgcn_mfma_i32_16x16x64_i8(kfrag, qf0, zero, 0, 0, 0);
      const v4i a1 = __builtin_amdgcn_mfma_i32_16x16x64_i8(kfrag, qf1, zero, 0, 0, 0);
      const float ks[4] = {ks4.x, ks4.y, ks4.z, ks4.w};
      #pragma unroll
      for (int r = 0; r < 4; ++r) {
        const float v0 = (float)a0[r] * (qs0 * ks[r]);
        const float v1 = (float)a1[r] * (qs1 * ks[r]);
        s26[0][t][r] = v0; vmax0 = fmaxf(vmax0, v0);
        s26[1][t][r] = v1; vmax1 = fmaxf(vmax1, v1);
      }
    }
    vmax0 = fmaxf(vmax0, __shfl_xor(vmax0, 16));
    vmax0 = fmaxf(vmax0, __shfl_xor(vmax0, 32));
    vmax1 = fmaxf(vmax1, __shfl_xor(vmax1, 16));
    vmax1 = fmaxf(vmax1, __shfl_xor(vmax1, 32));
    if (quad == 0) { red_max[0][n][w] = vmax0; red_max[1][n][w] = vmax1; }
  }
  __syncthreads();  // bar1

  // ---- Phase B: 2a(t0) ----
  {
    const float4 rm = *(const float4*)&red_max[0][n][0];
    const float mx26 = fmaxf(fmaxf(rm.x, rm.y), fmaxf(rm.z, rm.w));
    float sum, amax;
    softmax_exp_tile(s26[0], mx26, pt4, sum, amax);
    if (quad == 0) { red_sum[0][n][w] = sum; red_amax[0][n][w] = amax; }
  }
  __syncthreads();  // bar2

  // ---- Phase C: 2b(t0) -> PhT[0]  +  2a(t1) ----
  {
    const float4 rs = *(const float4*)&red_sum[0][n][0];
    const float4 ra = *(const float4*)&red_amax[0][n][0];
    float denom = (rs.x + rs.y) + (rs.z + rs.w);
    denom = __fadd_rn(denom, 1e-9f);
    const float rden = 1.0f / denom;
    const float am = fmaxf(fmaxf(ra.x, ra.y), fmaxf(ra.z, ra.w));
    float ps = (am * rden) / 127.0f;
    if (ps == 0.f) ps = 1.f;
    if (w == 0 && quad == 0) psa[0][n] = ps;
    const float t127 = 127.0f / am;
    quant_pack_tile(s26[0], t127, &PhT[0][n * PSTR], w, quad);

    const float4 rm = *(const float4*)&red_max[1][n][0];
    const float mx26 = fmaxf(fmaxf(rm.x, rm.y), fmaxf(rm.z, rm.w));
    float sum, amax;
    softmax_exp_tile(s26[1], mx26, pt4, sum, amax);
    if (quad == 0) { red_sum[1][n][w] = sum; red_amax[1][n][w] = amax; }
  }
  __syncthreads();  // bar3

  const _Float16* vbase = vt2 + ((size_t)hb * 16 * 64 + (w * 16 + n)) * 32 + quad * 8;

  // ---- Phase D: PV(t0)  +  2b(t1) -> PhT[1] ----
  {
    const v4f acc0 = pv_tile(vbase, &PhT[0][n * PSTR + quad * 8]);

    const float4 rs = *(const float4*)&red_sum[1][n][0];
    const float4 ra = *(const float4*)&red_amax[1][n][0];
    float denom = (rs.x + rs.y) + (rs.z + rs.w);
    denom = __fadd_rn(denom, 1e-9f);
    const float rden = 1.0f / denom;
    const float am = fmaxf(fmaxf(ra.x, ra.y), fmaxf(ra.z, ra.w));
    float ps = (am * rden) / 127.0f;
    if (ps == 0.f) ps = 1.f;
    if (w == 0 && quad == 0) psa[1][n] = ps;
    const float t127 = 127.0f / am;
    quant_pack_tile(s26[1], t127, &PhT[1][n * PSTR], w, quad);

    #pragma unroll
    for (int r = 0; r < 4; ++r) {
      const int row = quad * 4 + r;
      ctx[((size_t)bz * SEQ + q0 + row) * HID + (size_t)hh * HDIM + w * 16 + n] =
          acc0[r] * psa[0][row];
    }
  }
  __syncthreads();  // bar4

  // ---- Phase E: PV(t1) ----
  {
    const v4f acc1 = pv_tile(vbase, &PhT[1][n * PSTR + quad * 8]);
    #pragma unroll
    for (int r = 0; r < 4; ++r) {
      const int row = quad * 4 + r;
      ctx[((size_t)bz * SEQ + q0 + 16 + row) * HID + (size_t)hh * HDIM + w * 16 + n] =
          acc1[r] * psa[1][row];
    }
  }
}

// --------------------------------------------------------------------------
extern "C" void kernel_launch(void* const* d_in, const int* in_sizes, int n_in,
                              void* d_out, int out_size, void* d_ws, size_t ws_size,
                              hipStream_t stream) {
  (void)in_sizes; (void)n_in; (void)out_size; (void)ws_size;
  const float* hs = (const float*)d_in[0];
  const float* Wq = (const float*)d_in[1];
  const float* bq = (const float*)d_in[2];
  const float* Wk = (const float*)d_in[3];
  const float* bk = (const float*)d_in[4];
  const float* Wv = (const float*)d_in[5];
  const float* bv = (const float*)d_in[6];
  const float* Wo = (const float*)d_in[7];
  const float* bo = (const float*)d_in[8];
  float* out = (float*)d_out;

  char* ws = (char*)d_ws;
  size_t off = 0;
  auto alloc = [&](size_t bytes) -> char* {
    char* p = ws + off;
    off += (bytes + 255) & ~(size_t)255;
    return p;
  };
  signed char* qx  = (signed char*)alloc((size_t)R_TOT * HID);
  float*       sx  = (float*)alloc((size_t)R_TOT * 4);
  signed char* qwq = (signed char*)alloc((size_t)HID * HID);
  signed char* qwk = (signed char*)alloc((size_t)HID * HID);
  signed char* qwv = (signed char*)alloc((size_t)HID * HID);
  signed char* qwo = (signed char*)alloc((size_t)HID * HID);
  float*       swq = (float*)alloc((size_t)HID * 4);
  float*       swk = (float*)alloc((size_t)HID * 4);
  float*       swv = (float*)alloc((size_t)HID * 4);
  float*       swo = (float*)alloc((size_t)HID * 4);
  signed char* qqd = (signed char*)alloc((size_t)R_TOT * HID);
  float*       qqs = (float*)alloc((size_t)BATCH * NHEAD * SEQ * 4);
  signed char* qkd = (signed char*)alloc((size_t)R_TOT * HID);
  float*       qks = (float*)alloc((size_t)BATCH * NHEAD * SEQ * 4);
  float*       ctx = (float*)alloc((size_t)R_TOT * HID * 4);
  _Float16*    vt2 = (_Float16*)alloc((size_t)BATCH * NHEAD * HDIM * SEQ * 2);
  // alias: qx/sx are dead after the QKV projections
  signed char* qc  = qx;
  float*       scs = sx;

  quant_all<<<R_TOT + 4 * HID, 256, 0, stream>>>(
      hs, Wq, Wk, Wv, Wo, qx, sx,
      qwq, qwk, qwv, qwo, swq, swk, swv, swo);

  proj_qkv<<<dim3(R_TOT / 128, HID / 64, 3), 256, 0, stream>>>(
      qx, sx, qwq, swq, bq, qqd, qqs,
      qwk, swk, bk, qkd, qks,
      qwv, swv, bv, vt2);

  attn_kernel<<<dim3(SEQ / 32, NHEAD, BATCH), 256, 0, stream>>>(
      qqd, qqs, qkd, qks, vt2, ctx, g_pla);

  quant_rows<<<R_TOT, 256, 0, stream>>>(ctx, qc, scs);
  proj_out<<<dim3(R_TOT / 128, HID / 64), 256, 0, stream>>>(
      qc, scs, qwo, swo, bo, out);
}